// Round 2
// baseline (403.545 us; speedup 1.0000x reference)
//
#include <hip/hip_runtime.h>

#define E_DIM 1024
#define NHEADS 16
#define HDIM 64
#define BATCH 2
#define SEQ 2048
#define M_TOT (BATCH*SEQ)   // 4096

typedef _Float16 f16;
typedef _Float16 half4 __attribute__((ext_vector_type(4)));
typedef float floatx4 __attribute__((ext_vector_type(4)));

// ---------------------------------------------------------------------------
// Kernel 1: fused f32->f16 QKV projection GEMM.
//   out[z] = f16( x @ W[z] + b[z] ),  z in {0:Q, 1:K, 2:V}
// Tiles: BM=64, BN=64, BK=32. 256 threads = 4 waves (2x2), each wave 32x32.
// MFMA: v_mfma_f32_16x16x16f16 (classic verified layout).
// ---------------------------------------------------------------------------
__global__ __launch_bounds__(256) void qkv_proj(
    const float* __restrict__ x,
    const float* __restrict__ Wq, const float* __restrict__ bq,
    const float* __restrict__ Wk, const float* __restrict__ bk,
    const float* __restrict__ Wv, const float* __restrict__ bv,
    f16* __restrict__ qh, f16* __restrict__ kh, f16* __restrict__ vh)
{
    const int z = blockIdx.z;
    const float* W    = (z == 0) ? Wq : (z == 1) ? Wk : Wv;
    const float* bias = (z == 0) ? bq : (z == 1) ? bk : bv;
    f16* out          = (z == 0) ? qh : (z == 1) ? kh : vh;

    const int n0 = blockIdx.x * 64;
    const int m0 = blockIdx.y * 64;
    const int tid  = threadIdx.x;
    const int lane = tid & 63;
    const int w  = tid >> 6;        // wave id 0..3
    const int wm = w >> 1, wn = w & 1;
    const int g  = lane >> 4, r = lane & 15;

    // +8 f16 pad (stride 40 halfwords = 80B) to spread LDS banks
    __shared__ f16 Alds[64][40];    // x tile   [m][k]
    __shared__ f16 Btlds[64][40];   // W tile transposed: [n][k]

    floatx4 acc[2][2];
    #pragma unroll
    for (int i = 0; i < 2; i++)
        #pragma unroll
        for (int j = 0; j < 2; j++)
            acc[i][j] = (floatx4){0.f, 0.f, 0.f, 0.f};

    for (int k0 = 0; k0 < E_DIM; k0 += 32) {
        // --- stage A: x[m0..m0+64)[k0..k0+32) as f16, float4 loads ---
        #pragma unroll
        for (int t = 0; t < 2; t++) {
            int idx = tid + t * 256;          // 512 chunks of 4 f32
            int mm = idx >> 3;                // 8 chunks per 32-wide row
            int kc = (idx & 7) * 4;
            float4 v4 = *(const float4*)&x[(size_t)(m0 + mm) * E_DIM + k0 + kc];
            half4 hv = { (f16)v4.x, (f16)v4.y, (f16)v4.z, (f16)v4.w };
            *(half4*)&Alds[mm][kc] = hv;
        }
        // --- stage Bt: W[k0..+32)[n0..+64) transposed to [n][k] ---
        #pragma unroll
        for (int t = 0; t < 2; t++) {
            int idx = tid + t * 256;          // 512 chunks of 4 f32
            int kk = idx >> 4;                // 16 chunks per 64-wide row
            int cc = (idx & 15) * 4;
            float4 v4 = *(const float4*)&W[(size_t)(k0 + kk) * E_DIM + n0 + cc];
            Btlds[cc + 0][kk] = (f16)v4.x;
            Btlds[cc + 1][kk] = (f16)v4.y;
            Btlds[cc + 2][kk] = (f16)v4.z;
            Btlds[cc + 3][kk] = (f16)v4.w;
        }
        __syncthreads();

        #pragma unroll
        for (int ks = 0; ks < 32; ks += 16) {
            half4 a[2], b[2];
            #pragma unroll
            for (int i = 0; i < 2; i++)
                a[i] = *(const half4*)&Alds[wm * 32 + i * 16 + r][ks + g * 4];
            #pragma unroll
            for (int j = 0; j < 2; j++)
                b[j] = *(const half4*)&Btlds[wn * 32 + j * 16 + r][ks + g * 4];
            #pragma unroll
            for (int i = 0; i < 2; i++)
                #pragma unroll
                for (int j = 0; j < 2; j++)
                    acc[i][j] = __builtin_amdgcn_mfma_f32_16x16x16f16(
                        a[i], b[j], acc[i][j], 0, 0, 0);
        }
        __syncthreads();
    }

    // epilogue: +bias, convert to f16, store
    #pragma unroll
    for (int i = 0; i < 2; i++)
        #pragma unroll
        for (int j = 0; j < 2; j++) {
            int col = n0 + wn * 32 + j * 16 + r;
            float bb = bias[col];
            #pragma unroll
            for (int rr = 0; rr < 4; rr++) {
                int row = m0 + wm * 32 + i * 16 + g * 4 + rr;
                out[(size_t)row * E_DIM + col] = (f16)(acc[i][j][rr] + bb);
            }
        }
}

// ---------------------------------------------------------------------------
// Kernel 2: flash attention fwd (no scale, per reference).
// 1 block per (b, h, 128 q-rows). 4 waves x 32 q-rows. K-tiles of 64.
// ---------------------------------------------------------------------------
__global__ __launch_bounds__(256) void attn(
    const f16* __restrict__ qh, const f16* __restrict__ kh,
    const f16* __restrict__ vh, float* __restrict__ out)
{
    const int b  = blockIdx.z, h = blockIdx.y;
    const int q0 = blockIdx.x * 128;
    const int tid  = threadIdx.x;
    const int lane = tid & 63;
    const int w  = tid >> 6;
    const int g  = lane >> 4, r = lane & 15;

    __shared__ f16 Klds[64][72];      // [k_row][d]   (+8 pad)
    __shared__ f16 Vt[64][72];        // [d][k_row]   (+8 pad)
    __shared__ f16 Plds[4][32][72];   // per-wave P round-trip

    const size_t base = ((size_t)b * SEQ) * E_DIM + (size_t)h * HDIM;

    // Q fragments in registers: rows q0 + w*32 + i*16 + r, d = dk*16 + g*4 + j
    half4 aq[2][4];
    #pragma unroll
    for (int i = 0; i < 2; i++)
        #pragma unroll
        for (int dk = 0; dk < 4; dk++) {
            int row = q0 + w * 32 + i * 16 + r;
            aq[i][dk] = *(const half4*)&qh[base + (size_t)row * E_DIM + dk * 16 + g * 4];
        }

    float m_run[2][4], l_run[2][4];
    floatx4 acco[2][4];
    #pragma unroll
    for (int i = 0; i < 2; i++)
        #pragma unroll
        for (int rr = 0; rr < 4; rr++) { m_run[i][rr] = -1e30f; l_run[i][rr] = 0.f; }
    #pragma unroll
    for (int i = 0; i < 2; i++)
        #pragma unroll
        for (int dj = 0; dj < 4; dj++)
            acco[i][dj] = (floatx4){0.f, 0.f, 0.f, 0.f};

    for (int kt = 0; kt < SEQ; kt += 64) {
        // --- stage K tile [64][64] and V^T tile [64][64] ---
        #pragma unroll
        for (int t = 0; t < 2; t++) {
            int idx = tid + t * 256;          // 512 chunks of 8 f16
            int kr = idx >> 3;
            int dc = (idx & 7) * 8;
            const f16* src = &kh[base + (size_t)(kt + kr) * E_DIM + dc];
            *(uint4*)&Klds[kr][dc] = *(const uint4*)src;
            half4 va = *(const half4*)&vh[base + (size_t)(kt + kr) * E_DIM + dc];
            half4 vb = *(const half4*)&vh[base + (size_t)(kt + kr) * E_DIM + dc + 4];
            #pragma unroll
            for (int e = 0; e < 4; e++) {
                Vt[dc + e][kr]     = va[e];
                Vt[dc + 4 + e][kr] = vb[e];
            }
        }
        __syncthreads();

        // --- S = Q K^T for this tile: sc[i][kb], kb = 16-col block ---
        floatx4 sc[2][4];
        #pragma unroll
        for (int i = 0; i < 2; i++)
            #pragma unroll
            for (int kb = 0; kb < 4; kb++)
                sc[i][kb] = (floatx4){0.f, 0.f, 0.f, 0.f};
        #pragma unroll
        for (int kb = 0; kb < 4; kb++) {
            half4 bkf[4];
            #pragma unroll
            for (int dk = 0; dk < 4; dk++)
                bkf[dk] = *(const half4*)&Klds[kb * 16 + r][dk * 16 + g * 4];
            #pragma unroll
            for (int i = 0; i < 2; i++)
                #pragma unroll
                for (int dk = 0; dk < 4; dk++)
                    sc[i][kb] = __builtin_amdgcn_mfma_f32_16x16x16f16(
                        aq[i][dk], bkf[dk], sc[i][kb], 0, 0, 0);
        }

        // --- online softmax (rows owned per-lane via C/D layout) ---
        #pragma unroll
        for (int i = 0; i < 2; i++) {
            #pragma unroll
            for (int rr = 0; rr < 4; rr++) {
                float tm = fmaxf(fmaxf(sc[i][0][rr], sc[i][1][rr]),
                                 fmaxf(sc[i][2][rr], sc[i][3][rr]));
                #pragma unroll
                for (int mask = 8; mask >= 1; mask >>= 1)
                    tm = fmaxf(tm, __shfl_xor(tm, mask, 64));
                float mn = fmaxf(m_run[i][rr], tm);
                float alpha = __expf(m_run[i][rr] - mn);
                m_run[i][rr] = mn;
                float rs = 0.f;
                #pragma unroll
                for (int kb = 0; kb < 4; kb++) {
                    float p = __expf(sc[i][kb][rr] - mn);
                    sc[i][kb][rr] = p;
                    rs += p;
                }
                #pragma unroll
                for (int mask = 8; mask >= 1; mask >>= 1)
                    rs += __shfl_xor(rs, mask, 64);
                l_run[i][rr] = l_run[i][rr] * alpha + rs;
                #pragma unroll
                for (int dj = 0; dj < 4; dj++)
                    acco[i][dj][rr] *= alpha;
                #pragma unroll
                for (int kb = 0; kb < 4; kb++)
                    Plds[w][i * 16 + g * 4 + rr][kb * 16 + r] = (f16)sc[i][kb][rr];
            }
        }
        __syncthreads();   // order Plds writes before reads; cheap, safe

        // --- O += P V ---
        #pragma unroll
        for (int i = 0; i < 2; i++) {
            half4 pf[4];
            #pragma unroll
            for (int kk = 0; kk < 4; kk++)
                pf[kk] = *(const half4*)&Plds[w][i * 16 + r][kk * 16 + g * 4];
            #pragma unroll
            for (int dj = 0; dj < 4; dj++) {
                #pragma unroll
                for (int kk = 0; kk < 4; kk++) {
                    half4 vf = *(const half4*)&Vt[dj * 16 + r][kk * 16 + g * 4];
                    acco[i][dj] = __builtin_amdgcn_mfma_f32_16x16x16f16(
                        pf[kk], vf, acco[i][dj], 0, 0, 0);
                }
            }
        }
        __syncthreads();   // protect K/Vt before next tile's staging
    }

    // --- epilogue: out = acc / l, f32 ---
    #pragma unroll
    for (int i = 0; i < 2; i++)
        #pragma unroll
        for (int dj = 0; dj < 4; dj++)
            #pragma unroll
            for (int rr = 0; rr < 4; rr++) {
                int row = q0 + w * 32 + i * 16 + g * 4 + rr;
                int col = dj * 16 + r;
                out[(size_t)(b * SEQ + row) * E_DIM + h * HDIM + col] =
                    acco[i][dj][rr] / l_run[i][rr];
            }
}

extern "C" void kernel_launch(void* const* d_in, const int* in_sizes, int n_in,
                              void* d_out, int out_size, void* d_ws, size_t ws_size,
                              hipStream_t stream) {
    const float* x  = (const float*)d_in[0];
    const float* Wq = (const float*)d_in[1];
    const float* bq = (const float*)d_in[2];
    const float* Wk = (const float*)d_in[3];
    const float* bk = (const float*)d_in[4];
    const float* Wv = (const float*)d_in[5];
    const float* bv = (const float*)d_in[6];
    float* out = (float*)d_out;

    size_t qkv_elems = (size_t)M_TOT * E_DIM;
    f16* qh = (f16*)d_ws;
    f16* kh = qh + qkv_elems;
    f16* vh = kh + qkv_elems;
    if (ws_size < 3 * qkv_elems * sizeof(f16)) return;  // need 24 MB scratch

    qkv_proj<<<dim3(E_DIM / 64, M_TOT / 64, 3), 256, 0, stream>>>(
        x, Wq, bq, Wk, bk, Wv, bv, qh, kh, vh);
    attn<<<dim3(SEQ / 128, NHEADS, BATCH), 256, 0, stream>>>(qh, kh, vh, out);
}

// Round 3
// 293.476 us; speedup vs baseline: 1.3751x; 1.3751x over previous
//
#include <hip/hip_runtime.h>

#define E_DIM 1024
#define NHEADS 16
#define HDIM 64
#define BATCH 2
#define SEQ 2048
#define M_TOT (BATCH*SEQ)   // 4096

typedef _Float16 f16;
typedef _Float16 half8 __attribute__((ext_vector_type(8)));
typedef _Float16 half2v __attribute__((ext_vector_type(2)));
typedef float floatx4 __attribute__((ext_vector_type(4)));

#define MFMA16x32(a,b,c) __builtin_amdgcn_mfma_f32_16x16x32_f16((a),(b),(c),0,0,0)

// ---------------------------------------------------------------------------
// Kernel 1: fused f32->f16 QKV projection GEMM.  out[z] = f16(x @ W[z] + b[z])
// 128x128 tile, BK=32, 4 waves (2x2) each 64x64. mfma_f32_16x16x32_f16.
// LDS [128][32] f16 linear, XOR swizzle keyed on (row>>2)&3 (16B granular).
// ---------------------------------------------------------------------------
__global__ __launch_bounds__(256) void qkv_proj(
    const float* __restrict__ x,
    const float* __restrict__ Wq, const float* __restrict__ bq,
    const float* __restrict__ Wk, const float* __restrict__ bk,
    const float* __restrict__ Wv, const float* __restrict__ bv,
    f16* __restrict__ qh, f16* __restrict__ kh, f16* __restrict__ vh)
{
    // XCD-aware remap (768 = 8 * 96, bijective)
    const int flat = blockIdx.x;
    const int rb = (flat & 7) * 96 + (flat >> 3);
    const int nt = rb & 7;          // 8 n-tiles
    const int mt = (rb >> 3) & 31;  // 32 m-tiles
    const int z  = rb >> 8;         // 3 matrices

    const float* W    = (z == 0) ? Wq : (z == 1) ? Wk : Wv;
    const float* bias = (z == 0) ? bq : (z == 1) ? bk : bv;
    f16* out          = (z == 0) ? qh : (z == 1) ? kh : vh;

    const int m0 = mt * 128, n0 = nt * 128;
    const int tid = threadIdx.x;
    const int lane = tid & 63;
    const int w  = tid >> 6;
    const int wm = w >> 1, wn = w & 1;
    const int g  = lane >> 4, r = lane & 15;

    __shared__ f16 Al[128 * 32];   // x tile  [m][k], swizzled
    __shared__ f16 Bl[128 * 32];   // W tile transposed [n][k], swizzled

    floatx4 acc[4][4];
    #pragma unroll
    for (int i = 0; i < 4; i++)
        #pragma unroll
        for (int j = 0; j < 4; j++)
            acc[i][j] = (floatx4){0.f, 0.f, 0.f, 0.f};

    for (int k0 = 0; k0 < E_DIM; k0 += 32) {
        // stage A: 128x32 f32 -> f16, one half8 (16B) ds_write per unit
        #pragma unroll
        for (int it = 0; it < 2; it++) {
            int idx = tid + it * 256;            // 512 units
            int mm = idx >> 2, kc = (idx & 3) * 8;
            const float* s = &x[(size_t)(m0 + mm) * E_DIM + k0 + kc];
            float4 u = *(const float4*)s;
            float4 v = *(const float4*)(s + 4);
            half8 hv = {(f16)u.x,(f16)u.y,(f16)u.z,(f16)u.w,
                        (f16)v.x,(f16)v.y,(f16)v.z,(f16)v.w};
            *(half8*)&Al[mm * 32 + (kc ^ (((mm >> 2) & 3) << 3))] = hv;
        }
        // stage B (transpose): 2 k-rows x 4 n per unit; packed f16 pair writes
        #pragma unroll
        for (int it = 0; it < 2; it++) {
            int idx = tid + it * 256;            // 512 units
            int kk = (idx >> 5) << 1, nn = (idx & 31) * 4;
            const float* w0 = &W[(size_t)(k0 + kk) * E_DIM + n0 + nn];
            float4 a = *(const float4*)w0;
            float4 b = *(const float4*)(w0 + E_DIM);
            float av[4] = {a.x, a.y, a.z, a.w};
            float bv4[4] = {b.x, b.y, b.z, b.w};
            #pragma unroll
            for (int e = 0; e < 4; e++) {
                int row = nn + e;
                half2v p = {(f16)av[e], (f16)bv4[e]};
                *(half2v*)&Bl[row * 32 + (kk ^ (((row >> 2) & 3) << 3))] = p;
            }
        }
        __syncthreads();

        half8 af[4], bf[4];
        #pragma unroll
        for (int i = 0; i < 4; i++) {
            int row = wm * 64 + i * 16 + r;
            af[i] = *(const half8*)&Al[row * 32 + ((g * 8) ^ (((row >> 2) & 3) << 3))];
        }
        #pragma unroll
        for (int j = 0; j < 4; j++) {
            int row = wn * 64 + j * 16 + r;
            bf[j] = *(const half8*)&Bl[row * 32 + ((g * 8) ^ (((row >> 2) & 3) << 3))];
        }
        #pragma unroll
        for (int i = 0; i < 4; i++)
            #pragma unroll
            for (int j = 0; j < 4; j++)
                acc[i][j] = MFMA16x32(af[i], bf[j], acc[i][j]);
        __syncthreads();
    }

    // epilogue: +bias, f16 store. C/D: col = lane&15, row = g*4 + reg.
    #pragma unroll
    for (int j = 0; j < 4; j++) {
        int col = n0 + wn * 64 + j * 16 + r;
        float bb = bias[col];
        #pragma unroll
        for (int i = 0; i < 4; i++)
            #pragma unroll
            for (int rr = 0; rr < 4; rr++) {
                int row = m0 + wm * 64 + i * 16 + g * 4 + rr;
                out[(size_t)row * E_DIM + col] = (f16)(acc[i][j][rr] + bb);
            }
    }
}

// ---------------------------------------------------------------------------
// Kernel 2: flash attention fwd (no 1/sqrt(d) scale, per reference).
// QBLK=64 (grid 1024 = 4 blocks/CU), 4 waves x 16 q-rows, KVBLK=64.
// K_s swizzle key (row&7); V_s (transposed) key ((row^(row>>3))&7); P_s (row&7).
// ---------------------------------------------------------------------------
__global__ __launch_bounds__(256) void attn(
    const f16* __restrict__ qh, const f16* __restrict__ kh,
    const f16* __restrict__ vh, float* __restrict__ out)
{
    const int flat = blockIdx.x;                 // 1024 blocks
    const int rb = (flat & 7) * 128 + (flat >> 3);
    const int qb = rb & 31;
    const int hh = (rb >> 5) & 15;
    const int b  = rb >> 9;
    const int q0 = qb * 64;

    const int tid = threadIdx.x;
    const int lane = tid & 63;
    const int w = tid >> 6;
    const int g = lane >> 4, r = lane & 15;

    __shared__ f16 K_s[64 * 64];       // [kv][d] swizzled
    __shared__ f16 V_s[64 * 64];       // [d][kv] swizzled (transposed)
    __shared__ f16 P_s[4][16 * 64];    // per-wave [q][kv] swizzled

    const size_t base = ((size_t)b * SEQ) * E_DIM + (size_t)hh * HDIM;

    // Q fragments (rows q0 + w*16 + r), k-map d = dk*32 + g*8 + j
    half8 aq[2];
    {
        const f16* qp = &qh[base + (size_t)(q0 + w * 16 + r) * E_DIM];
        aq[0] = *(const half8*)&qp[g * 8];
        aq[1] = *(const half8*)&qp[32 + g * 8];
    }

    float m_run[4], l_run[4];
    floatx4 acco[4];
    #pragma unroll
    for (int rr = 0; rr < 4; rr++) { m_run[rr] = -1e30f; l_run[rr] = 0.f; }
    #pragma unroll
    for (int dj = 0; dj < 4; dj++) acco[dj] = (floatx4){0.f, 0.f, 0.f, 0.f};

    for (int kt = 0; kt < SEQ; kt += 64) {
        if (kt) __syncthreads();   // previous tile's K_s/V_s reads complete
        // --- stage K [kv][d] and V^T [d][kv] ---
        {
            int kr = tid >> 2, dc = (tid & 3) << 4;
            int swk = (kr & 7) << 3;
            const f16* kp = &kh[base + (size_t)(kt + kr) * E_DIM + dc];
            uint4 k0v = *(const uint4*)kp;
            uint4 k1v = *(const uint4*)(kp + 8);
            *(uint4*)&K_s[kr * 64 + (dc ^ swk)]       = k0v;
            *(uint4*)&K_s[kr * 64 + ((dc + 8) ^ swk)] = k1v;
            const f16* vp = &vh[base + (size_t)(kt + kr) * E_DIM + dc];
            half8 v0 = *(const half8*)vp;
            half8 v1 = *(const half8*)(vp + 8);
            #pragma unroll
            for (int e = 0; e < 16; e++) {
                int drow = dc + e;
                f16 val = (e < 8) ? v0[e] : v1[e - 8];
                int swv = ((drow ^ (drow >> 3)) & 7) << 3;
                V_s[drow * 64 + (kr ^ swv)] = val;
            }
        }
        __syncthreads();

        // --- S = Q K^T.  sc[kb]: C/D rows = q (g*4+rr), cols = kv (kb*16+r) ---
        floatx4 sc[4];
        #pragma unroll
        for (int kb = 0; kb < 4; kb++) sc[kb] = (floatx4){0.f, 0.f, 0.f, 0.f};
        #pragma unroll
        for (int kb = 0; kb < 4; kb++) {
            int krow = kb * 16 + r;
            int swk = (krow & 7) << 3;
            const f16* kbase = &K_s[krow * 64];
            half8 b0 = *(const half8*)&kbase[(g * 8) ^ swk];
            half8 b1 = *(const half8*)&kbase[(32 + g * 8) ^ swk];
            sc[kb] = MFMA16x32(aq[0], b0, sc[kb]);
            sc[kb] = MFMA16x32(aq[1], b1, sc[kb]);
        }

        // --- online softmax; rows q = g*4+rr, reduce over r-lanes ---
        #pragma unroll
        for (int rr = 0; rr < 4; rr++) {
            float tm = fmaxf(fmaxf(sc[0][rr], sc[1][rr]),
                             fmaxf(sc[2][rr], sc[3][rr]));
            #pragma unroll
            for (int mask = 8; mask >= 1; mask >>= 1)
                tm = fmaxf(tm, __shfl_xor(tm, mask, 64));
            float mn = fmaxf(m_run[rr], tm);
            float alpha = __expf(m_run[rr] - mn);
            m_run[rr] = mn;
            float rs = 0.f;
            #pragma unroll
            for (int kb = 0; kb < 4; kb++) {
                float p = __expf(sc[kb][rr] - mn);
                sc[kb][rr] = p;
                rs += p;
            }
            #pragma unroll
            for (int mask = 8; mask >= 1; mask >>= 1)
                rs += __shfl_xor(rs, mask, 64);
            l_run[rr] = l_run[rr] * alpha + rs;
            #pragma unroll
            for (int dj = 0; dj < 4; dj++) acco[dj][rr] *= alpha;
            int prow = g * 4 + rr;
            int swp = (prow & 7) << 3;
            #pragma unroll
            for (int kb = 0; kb < 4; kb++)
                P_s[w][prow * 64 + ((kb * 16 + r) ^ swp)] = (f16)sc[kb][rr];
        }

        // --- O += P V  (per-wave P_s, no barrier needed) ---
        half8 pf[2];
        {
            int swp = (r & 7) << 3;
            pf[0] = *(const half8*)&P_s[w][r * 64 + ((g * 8) ^ swp)];
            pf[1] = *(const half8*)&P_s[w][r * 64 + ((32 + g * 8) ^ swp)];
        }
        #pragma unroll
        for (int dj = 0; dj < 4; dj++) {
            int drow = dj * 16 + r;
            int swv = ((drow ^ (drow >> 3)) & 7) << 3;
            const f16* vbase = &V_s[drow * 64];
            half8 vf0 = *(const half8*)&vbase[(g * 8) ^ swv];
            half8 vf1 = *(const half8*)&vbase[(32 + g * 8) ^ swv];
            acco[dj] = MFMA16x32(pf[0], vf0, acco[dj]);
            acco[dj] = MFMA16x32(pf[1], vf1, acco[dj]);
        }
    }

    // --- epilogue ---
    #pragma unroll
    for (int dj = 0; dj < 4; dj++)
        #pragma unroll
        for (int rr = 0; rr < 4; rr++) {
            int row = q0 + w * 16 + g * 4 + rr;
            out[(size_t)(b * SEQ + row) * E_DIM + hh * HDIM + dj * 16 + r] =
                acco[dj][rr] / l_run[rr];
        }
}

extern "C" void kernel_launch(void* const* d_in, const int* in_sizes, int n_in,
                              void* d_out, int out_size, void* d_ws, size_t ws_size,
                              hipStream_t stream) {
    const float* x  = (const float*)d_in[0];
    const float* Wq = (const float*)d_in[1];
    const float* bq = (const float*)d_in[2];
    const float* Wk = (const float*)d_in[3];
    const float* bk = (const float*)d_in[4];
    const float* Wv = (const float*)d_in[5];
    const float* bv = (const float*)d_in[6];
    float* out = (float*)d_out;

    size_t qkv_elems = (size_t)M_TOT * E_DIM;
    f16* qh = (f16*)d_ws;
    f16* kh = qh + qkv_elems;
    f16* vh = kh + qkv_elems;
    if (ws_size < 3 * qkv_elems * sizeof(f16)) return;  // need 24 MB scratch

    qkv_proj<<<dim3((E_DIM / 128) * (M_TOT / 128) * 3), 256, 0, stream>>>(
        x, Wq, bq, Wk, bk, Wv, bv, qh, kh, vh);
    attn<<<dim3((SEQ / 64) * NHEADS * BATCH), 256, 0, stream>>>(qh, kh, vh, out);
}

// Round 4
// 210.816 us; speedup vs baseline: 1.9142x; 1.3921x over previous
//
#include <hip/hip_runtime.h>

#define E_DIM 1024
#define NHEADS 16
#define HDIM 64
#define BATCH 2
#define SEQ 2048
#define M_TOT (BATCH*SEQ)   // 4096

typedef _Float16 f16;
typedef _Float16 half4 __attribute__((ext_vector_type(4)));
typedef _Float16 half8 __attribute__((ext_vector_type(8)));
typedef _Float16 half2v __attribute__((ext_vector_type(2)));
typedef float floatx4 __attribute__((ext_vector_type(4)));

#define MFMA16x32(a,b,c) __builtin_amdgcn_mfma_f32_16x16x32_f16((a),(b),(c),0,0,0)

// ---------------------------------------------------------------------------
// Prep: W [k][n] f32  ->  WT [n][k] f16   (64x64 tiles, LDS bounce)
// ---------------------------------------------------------------------------
__global__ __launch_bounds__(256) void transpose_w(
    const float* __restrict__ Wq, const float* __restrict__ Wk,
    const float* __restrict__ Wv,
    f16* __restrict__ WTq, f16* __restrict__ WTk, f16* __restrict__ WTv)
{
    const int z = blockIdx.z;
    const float* W = (z == 0) ? Wq : (z == 1) ? Wk : Wv;
    f16* WT        = (z == 0) ? WTq : (z == 1) ? WTk : WTv;

    const int k0 = blockIdx.x * 64, n0 = blockIdx.y * 64;
    const int tid = threadIdx.x;
    __shared__ f16 T[64][68];

    {
        const int tr = tid >> 4, tc = tid & 15;     // 4 k-rows x 4 n-cols each
        float4 f4[4];
        #pragma unroll
        for (int i = 0; i < 4; i++)
            f4[i] = *(const float4*)&W[(size_t)(k0 + tr * 4 + i) * E_DIM + n0 + tc * 4];
        #pragma unroll
        for (int j = 0; j < 4; j++) {
            float e0 = (j==0)?f4[0].x:(j==1)?f4[0].y:(j==2)?f4[0].z:f4[0].w;
            float e1 = (j==0)?f4[1].x:(j==1)?f4[1].y:(j==2)?f4[1].z:f4[1].w;
            float e2 = (j==0)?f4[2].x:(j==1)?f4[2].y:(j==2)?f4[2].z:f4[2].w;
            float e3 = (j==0)?f4[3].x:(j==1)?f4[3].y:(j==2)?f4[3].z:f4[3].w;
            half4 h = {(f16)e0, (f16)e1, (f16)e2, (f16)e3};
            *(half4*)&T[tc * 4 + j][tr * 4] = h;
        }
    }
    __syncthreads();
    {
        const int nn = tid >> 2, kk = (tid & 3) * 16;
        half8 a = *(const half8*)&T[nn][kk];
        half8 b = *(const half8*)&T[nn][kk + 8];
        f16* dst = &WT[(size_t)(n0 + nn) * E_DIM + k0 + kk];
        *(half8*)dst = a;
        *(half8*)(dst + 8) = b;
    }
}

// ---------------------------------------------------------------------------
// Kernel 1 (fast path): QKV GEMM, A = x f32, B = WT f16 [n][k].
// 128x128 tile, BK=32, 4 waves (2x2) each 64x64. mfma_f32_16x16x32_f16.
// ---------------------------------------------------------------------------
__global__ __launch_bounds__(256) void qkv_proj_v2(
    const float* __restrict__ x,
    const f16* __restrict__ WTq, const f16* __restrict__ WTk,
    const f16* __restrict__ WTv,
    const float* __restrict__ bq, const float* __restrict__ bk,
    const float* __restrict__ bv,
    f16* __restrict__ qh, f16* __restrict__ kh, f16* __restrict__ vh)
{
    const int flat = blockIdx.x;
    const int rb = (flat & 7) * 96 + (flat >> 3);
    const int nt = rb & 7;
    const int mt = (rb >> 3) & 31;
    const int z  = rb >> 8;

    const f16* WT     = (z == 0) ? WTq : (z == 1) ? WTk : WTv;
    const float* bias = (z == 0) ? bq : (z == 1) ? bk : bv;
    f16* out          = (z == 0) ? qh : (z == 1) ? kh : vh;

    const int m0 = mt * 128, n0 = nt * 128;
    const int tid = threadIdx.x;
    const int lane = tid & 63;
    const int w  = tid >> 6;
    const int wm = w >> 1, wn = w & 1;
    const int g  = lane >> 4, r = lane & 15;

    __shared__ f16 Al[128 * 32];
    __shared__ f16 Bl[128 * 32];

    floatx4 acc[4][4];
    #pragma unroll
    for (int i = 0; i < 4; i++)
        #pragma unroll
        for (int j = 0; j < 4; j++)
            acc[i][j] = (floatx4){0.f, 0.f, 0.f, 0.f};

    for (int k0 = 0; k0 < E_DIM; k0 += 32) {
        #pragma unroll
        for (int it = 0; it < 2; it++) {
            int idx = tid + it * 256;
            int mm = idx >> 2, kc = (idx & 3) * 8;
            const float* s = &x[(size_t)(m0 + mm) * E_DIM + k0 + kc];
            float4 u = *(const float4*)s;
            float4 v = *(const float4*)(s + 4);
            half8 hv = {(f16)u.x,(f16)u.y,(f16)u.z,(f16)u.w,
                        (f16)v.x,(f16)v.y,(f16)v.z,(f16)v.w};
            *(half8*)&Al[mm * 32 + (kc ^ (((mm >> 2) & 3) << 3))] = hv;
        }
        #pragma unroll
        for (int it = 0; it < 2; it++) {
            int idx = tid + it * 256;
            int nn = idx >> 2, kc = (idx & 3) * 8;
            half8 hv = *(const half8*)&WT[(size_t)(n0 + nn) * E_DIM + k0 + kc];
            *(half8*)&Bl[nn * 32 + (kc ^ (((nn >> 2) & 3) << 3))] = hv;
        }
        __syncthreads();

        half8 af[4], bf[4];
        #pragma unroll
        for (int i = 0; i < 4; i++) {
            int row = wm * 64 + i * 16 + r;
            af[i] = *(const half8*)&Al[row * 32 + ((g * 8) ^ (((row >> 2) & 3) << 3))];
        }
        #pragma unroll
        for (int j = 0; j < 4; j++) {
            int row = wn * 64 + j * 16 + r;
            bf[j] = *(const half8*)&Bl[row * 32 + ((g * 8) ^ (((row >> 2) & 3) << 3))];
        }
        #pragma unroll
        for (int i = 0; i < 4; i++)
            #pragma unroll
            for (int j = 0; j < 4; j++)
                acc[i][j] = MFMA16x32(af[i], bf[j], acc[i][j]);
        __syncthreads();
    }

    #pragma unroll
    for (int j = 0; j < 4; j++) {
        int col = n0 + wn * 64 + j * 16 + r;
        float bb = bias[col];
        #pragma unroll
        for (int i = 0; i < 4; i++)
            #pragma unroll
            for (int rr = 0; rr < 4; rr++) {
                int row = m0 + wm * 64 + i * 16 + g * 4 + rr;
                out[(size_t)row * E_DIM + col] = (f16)(acc[i][j][rr] + bb);
            }
    }
}

// ---------------------------------------------------------------------------
// Kernel 1 (fallback, round-3 proven): f32 W staging with on-the-fly transpose
// ---------------------------------------------------------------------------
__global__ __launch_bounds__(256) void qkv_proj(
    const float* __restrict__ x,
    const float* __restrict__ Wq, const float* __restrict__ bq,
    const float* __restrict__ Wk, const float* __restrict__ bk,
    const float* __restrict__ Wv, const float* __restrict__ bv,
    f16* __restrict__ qh, f16* __restrict__ kh, f16* __restrict__ vh)
{
    const int flat = blockIdx.x;
    const int rb = (flat & 7) * 96 + (flat >> 3);
    const int nt = rb & 7;
    const int mt = (rb >> 3) & 31;
    const int z  = rb >> 8;

    const float* W    = (z == 0) ? Wq : (z == 1) ? Wk : Wv;
    const float* bias = (z == 0) ? bq : (z == 1) ? bk : bv;
    f16* out          = (z == 0) ? qh : (z == 1) ? kh : vh;

    const int m0 = mt * 128, n0 = nt * 128;
    const int tid = threadIdx.x;
    const int lane = tid & 63;
    const int w  = tid >> 6;
    const int wm = w >> 1, wn = w & 1;
    const int g  = lane >> 4, r = lane & 15;

    __shared__ f16 Al[128 * 32];
    __shared__ f16 Bl[128 * 32];

    floatx4 acc[4][4];
    #pragma unroll
    for (int i = 0; i < 4; i++)
        #pragma unroll
        for (int j = 0; j < 4; j++)
            acc[i][j] = (floatx4){0.f, 0.f, 0.f, 0.f};

    for (int k0 = 0; k0 < E_DIM; k0 += 32) {
        #pragma unroll
        for (int it = 0; it < 2; it++) {
            int idx = tid + it * 256;
            int mm = idx >> 2, kc = (idx & 3) * 8;
            const float* s = &x[(size_t)(m0 + mm) * E_DIM + k0 + kc];
            float4 u = *(const float4*)s;
            float4 v = *(const float4*)(s + 4);
            half8 hv = {(f16)u.x,(f16)u.y,(f16)u.z,(f16)u.w,
                        (f16)v.x,(f16)v.y,(f16)v.z,(f16)v.w};
            *(half8*)&Al[mm * 32 + (kc ^ (((mm >> 2) & 3) << 3))] = hv;
        }
        #pragma unroll
        for (int it = 0; it < 2; it++) {
            int idx = tid + it * 256;
            int kk = (idx >> 5) << 1, nn = (idx & 31) * 4;
            const float* w0 = &W[(size_t)(k0 + kk) * E_DIM + n0 + nn];
            float4 a = *(const float4*)w0;
            float4 b = *(const float4*)(w0 + E_DIM);
            float av[4] = {a.x, a.y, a.z, a.w};
            float bv4[4] = {b.x, b.y, b.z, b.w};
            #pragma unroll
            for (int e = 0; e < 4; e++) {
                int row = nn + e;
                half2v p = {(f16)av[e], (f16)bv4[e]};
                *(half2v*)&Bl[row * 32 + (kk ^ (((row >> 2) & 3) << 3))] = p;
            }
        }
        __syncthreads();

        half8 af[4], bf[4];
        #pragma unroll
        for (int i = 0; i < 4; i++) {
            int row = wm * 64 + i * 16 + r;
            af[i] = *(const half8*)&Al[row * 32 + ((g * 8) ^ (((row >> 2) & 3) << 3))];
        }
        #pragma unroll
        for (int j = 0; j < 4; j++) {
            int row = wn * 64 + j * 16 + r;
            bf[j] = *(const half8*)&Bl[row * 32 + ((g * 8) ^ (((row >> 2) & 3) << 3))];
        }
        #pragma unroll
        for (int i = 0; i < 4; i++)
            #pragma unroll
            for (int j = 0; j < 4; j++)
                acc[i][j] = MFMA16x32(af[i], bf[j], acc[i][j]);
        __syncthreads();
    }

    #pragma unroll
    for (int j = 0; j < 4; j++) {
        int col = n0 + wn * 64 + j * 16 + r;
        float bb = bias[col];
        #pragma unroll
        for (int i = 0; i < 4; i++)
            #pragma unroll
            for (int rr = 0; rr < 4; rr++) {
                int row = m0 + wm * 64 + i * 16 + g * 4 + rr;
                out[(size_t)row * E_DIM + col] = (f16)(acc[i][j][rr] + bb);
            }
    }
}

// ---------------------------------------------------------------------------
// Kernel 2: flash attention, swapped QK^T (S^T = K·Q^T), P stays in registers.
// QBLK=128, 8 waves x 16 q-rows, 512 threads, KVBLK=64. LDS = K_s + V_s = 16KB.
// V stored transposed+column-permuted: V[kv][d] at V_s[d][kv_perm ^ swv(d)],
//   kv_perm = (kv&3) | ((kv>>4)&1)<<2 | ((kv>>2)&3)<<3 | (kv>>5)<<5
// so PV B-fragments are single half8 reads and match the in-register P slots.
// ---------------------------------------------------------------------------
__global__ __launch_bounds__(512, 4) void attn(
    const f16* __restrict__ qh, const f16* __restrict__ kh,
    const f16* __restrict__ vh, float* __restrict__ out)
{
    const int flat = blockIdx.x;                 // 512 blocks
    const int rb = (flat & 7) * 64 + (flat >> 3);
    const int qb = rb & 15;
    const int hh = (rb >> 4) & 15;
    const int b  = rb >> 8;
    const int q0 = qb * 128;

    const int tid = threadIdx.x;
    const int lane = tid & 63;
    const int w = tid >> 6;                      // 0..7
    const int g = lane >> 4, r = lane & 15;

    __shared__ f16 K_s[64 * 64];                 // [kv][d], swizzled
    __shared__ f16 V_s[64 * 64];                 // [d][kv_perm], swizzled

    const size_t base = ((size_t)b * SEQ) * E_DIM + (size_t)hh * HDIM;

    // Q fragment (B-operand of swapped QK^T): lane (g,r): Q[q0+w*16+r][h*32+g*8+j]
    half8 aq[2];
    {
        const f16* qp = &qh[base + (size_t)(q0 + w * 16 + r) * E_DIM];
        aq[0] = *(const half8*)&qp[g * 8];
        aq[1] = *(const half8*)&qp[32 + g * 8];
    }

    // staging indices (per thread: 8 f16 of one kv-row)
    const int skr = tid >> 3;                    // kv row 0..63
    const int sdc = (tid & 7) * 8;               // d chunk
    const int kvp = (skr & 3) | (((skr >> 4) & 1) << 2) |
                    (((skr >> 2) & 3) << 3) | ((skr >> 5) << 5);

    float m_run = -1e30f, l_run = 0.f;
    floatx4 acco[4];
    #pragma unroll
    for (int dj = 0; dj < 4; dj++) acco[dj] = (floatx4){0.f, 0.f, 0.f, 0.f};

    for (int kt = 0; kt < SEQ; kt += 64) {
        if (kt) __syncthreads();
        // --- stage K [kv][d] (vector) and V permuted-transposed (scalar) ---
        {
            const f16* kp = &kh[base + (size_t)(kt + skr) * E_DIM + sdc];
            half8 kv8 = *(const half8*)kp;
            *(half8*)&K_s[skr * 64 + (sdc ^ ((skr & 7) << 3))] = kv8;
            const f16* vp = &vh[base + (size_t)(kt + skr) * E_DIM + sdc];
            half8 v8 = *(const half8*)vp;
            #pragma unroll
            for (int e = 0; e < 8; e++) {
                int d = sdc + e;
                int swv = ((d ^ (d >> 3)) & 7) << 3;
                V_s[d * 64 + (kvp ^ swv)] = v8[e];
            }
        }
        __syncthreads();

        // --- S^T = K Q^T : lane (g,r) gets S^T[kb*16+g*4+rr][q=r] ---
        floatx4 sct[4];
        #pragma unroll
        for (int kb = 0; kb < 4; kb++) {
            int kvrow = kb * 16 + r;
            int swk = (kvrow & 7) << 3;
            const f16* kb_ = &K_s[kvrow * 64];
            half8 kf0 = *(const half8*)&kb_[(g * 8) ^ swk];
            half8 kf1 = *(const half8*)&kb_[(32 + g * 8) ^ swk];
            floatx4 c = (floatx4){0.f, 0.f, 0.f, 0.f};
            c = MFMA16x32(kf0, aq[0], c);
            c = MFMA16x32(kf1, aq[1], c);
            sct[kb] = c;
        }

        // --- softmax: q-row r owned 4-way across g; all P values lane-local ---
        float pm = -1e30f;
        #pragma unroll
        for (int kb = 0; kb < 4; kb++)
            #pragma unroll
            for (int rr = 0; rr < 4; rr++)
                pm = fmaxf(pm, sct[kb][rr]);
        pm = fmaxf(pm, __shfl_xor(pm, 16, 64));
        pm = fmaxf(pm, __shfl_xor(pm, 32, 64));
        float mn = fmaxf(m_run, pm);
        float alpha = __expf(m_run - mn);
        m_run = mn;
        float rs = 0.f;
        float p[4][4];
        #pragma unroll
        for (int kb = 0; kb < 4; kb++)
            #pragma unroll
            for (int rr = 0; rr < 4; rr++) {
                float e = __expf(sct[kb][rr] - mn);
                p[kb][rr] = e;
                rs += e;
            }
        rs += __shfl_xor(rs, 16, 64);
        rs += __shfl_xor(rs, 32, 64);
        l_run = l_run * alpha + rs;

        // broadcast alpha to accumulator rows (acc row q = g*4+rr)
        float af[4];
        #pragma unroll
        for (int rr = 0; rr < 4; rr++)
            af[rr] = __shfl(alpha, g * 4 + rr, 64);
        #pragma unroll
        for (int dj = 0; dj < 4; dj++)
            #pragma unroll
            for (int rr = 0; rr < 4; rr++)
                acco[dj][rr] *= af[rr];

        // pack P fragments: MFMA h slot (u*4+c) = p[h*2+u][c]
        half8 pa[2];
        #pragma unroll
        for (int h = 0; h < 2; h++) {
            half8 t = {(f16)p[h*2][0], (f16)p[h*2][1], (f16)p[h*2][2], (f16)p[h*2][3],
                       (f16)p[h*2+1][0], (f16)p[h*2+1][1], (f16)p[h*2+1][2], (f16)p[h*2+1][3]};
            pa[h] = t;
        }

        // --- O += P V : B-frag = one half8 per (dj,h) from permuted V_s ---
        #pragma unroll
        for (int dj = 0; dj < 4; dj++) {
            int d = dj * 16 + r;
            int swv = ((d ^ (d >> 3)) & 7) << 3;
            const f16* vb_ = &V_s[d * 64];
            half8 vf0 = *(const half8*)&vb_[(g * 8) ^ swv];
            half8 vf1 = *(const half8*)&vb_[(32 + g * 8) ^ swv];
            acco[dj] = MFMA16x32(pa[0], vf0, acco[dj]);
            acco[dj] = MFMA16x32(pa[1], vf1, acco[dj]);
        }
    }

    // --- epilogue: O[q=g*4+rr][d=dj*16+r] / l[q] ---
    float lf[4];
    #pragma unroll
    for (int rr = 0; rr < 4; rr++)
        lf[rr] = __shfl(l_run, g * 4 + rr, 64);
    #pragma unroll
    for (int dj = 0; dj < 4; dj++)
        #pragma unroll
        for (int rr = 0; rr < 4; rr++) {
            int row = q0 + w * 16 + g * 4 + rr;
            out[(size_t)(b * SEQ + row) * E_DIM + hh * HDIM + dj * 16 + r] =
                acco[dj][rr] / lf[rr];
        }
}

extern "C" void kernel_launch(void* const* d_in, const int* in_sizes, int n_in,
                              void* d_out, int out_size, void* d_ws, size_t ws_size,
                              hipStream_t stream) {
    const float* x  = (const float*)d_in[0];
    const float* Wq = (const float*)d_in[1];
    const float* bq = (const float*)d_in[2];
    const float* Wk = (const float*)d_in[3];
    const float* bk = (const float*)d_in[4];
    const float* Wv = (const float*)d_in[5];
    const float* bv = (const float*)d_in[6];
    float* out = (float*)d_out;

    const size_t qkv_elems = (size_t)M_TOT * E_DIM;          // 4M f16 each
    f16* qh = (f16*)d_ws;
    f16* kh = qh + qkv_elems;
    f16* vh = kh + qkv_elems;
    const size_t w_elems = (size_t)E_DIM * E_DIM;            // 1M f16 each
    f16* WTq = vh + qkv_elems;
    f16* WTk = WTq + w_elems;
    f16* WTv = WTk + w_elems;
    const size_t need_fast = (3 * qkv_elems + 3 * w_elems) * sizeof(f16); // 30 MB
    const size_t need_min  = 3 * qkv_elems * sizeof(f16);                 // 24 MB
    if (ws_size < need_min) return;

    if (ws_size >= need_fast) {
        transpose_w<<<dim3(16, 16, 3), 256, 0, stream>>>(Wq, Wk, Wv, WTq, WTk, WTv);
        qkv_proj_v2<<<dim3((E_DIM / 128) * (M_TOT / 128) * 3), 256, 0, stream>>>(
            x, WTq, WTk, WTv, bq, bk, bv, qh, kh, vh);
    } else {
        qkv_proj<<<dim3((E_DIM / 128) * (M_TOT / 128) * 3), 256, 0, stream>>>(
            x, Wq, bq, Wk, bk, Wv, bv, qh, kh, vh);
    }
    attn<<<dim3((SEQ / 128) * NHEADS * BATCH), 512, 0, stream>>>(qh, kh, vh, out);
}

// Round 5
// 183.189 us; speedup vs baseline: 2.2029x; 1.1508x over previous
//
#include <hip/hip_runtime.h>

#define E_DIM 1024
#define NHEADS 16
#define HDIM 64
#define BATCH 2
#define SEQ 2048
#define M_TOT (BATCH*SEQ)   // 4096

typedef _Float16 f16;
typedef _Float16 half4 __attribute__((ext_vector_type(4)));
typedef _Float16 half8 __attribute__((ext_vector_type(8)));
typedef _Float16 half2v __attribute__((ext_vector_type(2)));
typedef float floatx4 __attribute__((ext_vector_type(4)));

#define MFMA16x32(a,b,c) __builtin_amdgcn_mfma_f32_16x16x32_f16((a),(b),(c),0,0,0)

// async global->LDS, 16B per lane, LDS dest = wave-uniform base + lane*16
__device__ __forceinline__ void gll16(const f16* gsrc, f16* ldst) {
    __builtin_amdgcn_global_load_lds(
        (const __attribute__((address_space(1))) void*)gsrc,
        (__attribute__((address_space(3))) void*)ldst, 16, 0, 0);
}

// ---------------------------------------------------------------------------
// Prep A: x f32 -> f16
// ---------------------------------------------------------------------------
__global__ __launch_bounds__(256) void cvt_x(const float* __restrict__ x,
                                             f16* __restrict__ xh) {
    size_t i = ((size_t)blockIdx.x * 256 + threadIdx.x) * 8;
    float4 a = *(const float4*)&x[i];
    float4 b = *(const float4*)&x[i + 4];
    half8 h = {(f16)a.x,(f16)a.y,(f16)a.z,(f16)a.w,
               (f16)b.x,(f16)b.y,(f16)b.z,(f16)b.w};
    *(half8*)&xh[i] = h;
}

// ---------------------------------------------------------------------------
// Prep B: W [k][n] f32 -> WT [n][k] f16 (64x64 tiles, LDS bounce)
// ---------------------------------------------------------------------------
__global__ __launch_bounds__(256) void transpose_w(
    const float* __restrict__ Wq, const float* __restrict__ Wk,
    const float* __restrict__ Wv,
    f16* __restrict__ WTq, f16* __restrict__ WTk, f16* __restrict__ WTv)
{
    const int z = blockIdx.z;
    const float* W = (z == 0) ? Wq : (z == 1) ? Wk : Wv;
    f16* WT        = (z == 0) ? WTq : (z == 1) ? WTk : WTv;

    const int k0 = blockIdx.x * 64, n0 = blockIdx.y * 64;
    const int tid = threadIdx.x;
    __shared__ f16 T[64][68];

    {
        const int tr = tid >> 4, tc = tid & 15;
        float4 f4[4];
        #pragma unroll
        for (int i = 0; i < 4; i++)
            f4[i] = *(const float4*)&W[(size_t)(k0 + tr * 4 + i) * E_DIM + n0 + tc * 4];
        #pragma unroll
        for (int j = 0; j < 4; j++) {
            float e0 = (j==0)?f4[0].x:(j==1)?f4[0].y:(j==2)?f4[0].z:f4[0].w;
            float e1 = (j==0)?f4[1].x:(j==1)?f4[1].y:(j==2)?f4[1].z:f4[1].w;
            float e2 = (j==0)?f4[2].x:(j==1)?f4[2].y:(j==2)?f4[2].z:f4[2].w;
            float e3 = (j==0)?f4[3].x:(j==1)?f4[3].y:(j==2)?f4[3].z:f4[3].w;
            half4 h = {(f16)e0, (f16)e1, (f16)e2, (f16)e3};
            *(half4*)&T[tc * 4 + j][tr * 4] = h;
        }
    }
    __syncthreads();
    {
        const int nn = tid >> 2, kk = (tid & 3) * 16;
        half8 a = *(const half8*)&T[nn][kk];
        half8 b = *(const half8*)&T[nn][kk + 8];
        f16* dst = &WT[(size_t)(n0 + nn) * E_DIM + k0 + kk];
        *(half8*)dst = a;
        *(half8*)(dst + 8) = b;
    }
}

// ---------------------------------------------------------------------------
// Kernel 1 v3: pure-f16 GEMM, m97 structure.
// A = xh [4096][1024], B = WTall [3072][1024] (WTq/k/v contiguous).
// 128x128 tile, BK=64, global_load_lds(16B), pre-swizzled source,
// read swizzle key (row&7)<<3 (f16 units). 4 waves 2x2, each 64x64.
// ---------------------------------------------------------------------------
__global__ __launch_bounds__(256) void qkv_gemm(
    const f16* __restrict__ xh, const f16* __restrict__ WTall,
    const float* __restrict__ bq, const float* __restrict__ bk,
    const float* __restrict__ bv,
    f16* __restrict__ qh, f16* __restrict__ kh, f16* __restrict__ vh)
{
    const int flat = blockIdx.x;                  // 768 = 8*96
    const int rb = (flat & 7) * 96 + (flat >> 3);
    const int z   = rb >> 8;                      // 3 matrices
    const int ntl = rb & 7;                       // 8 n-tiles per z
    const int mt  = (rb >> 3) & 31;               // 32 m-tiles

    const float* bias = (z == 0) ? bq : (z == 1) ? bk : bv;
    f16* out          = (z == 0) ? qh : (z == 1) ? kh : vh;

    const int m0 = mt * 128;
    const int n0g = z * 1024 + ntl * 128;         // row in WTall
    const int tid = threadIdx.x;
    const int lane = tid & 63;
    const int w  = tid >> 6;
    const int wm = w >> 1, wn = w & 1;
    const int g  = lane >> 4, r = lane & 15;

    __shared__ f16 Al[128 * 64];
    __shared__ f16 Bl[128 * 64];

    // staging: chunk c (0..15) = rows c*8..c*8+8; lane: row c*8+(lane>>3),
    // source col pre-swizzled: ((lane&7) ^ (lane>>3)) * 8
    const int lrow = lane >> 3;
    const int lcol = ((lane & 7) ^ lrow) * 8;
    const f16* asrc = xh    + (size_t)(m0  + lrow) * E_DIM + lcol;
    const f16* bsrc = WTall + (size_t)(n0g + lrow) * E_DIM + lcol;

    floatx4 acc[4][4];
    #pragma unroll
    for (int i = 0; i < 4; i++)
        #pragma unroll
        for (int j = 0; j < 4; j++)
            acc[i][j] = (floatx4){0.f, 0.f, 0.f, 0.f};

    for (int k0 = 0; k0 < E_DIM; k0 += 64) {
        if (k0) __syncthreads();
        #pragma unroll
        for (int t = 0; t < 4; t++) {
            int c = w * 4 + t;
            gll16(asrc + (size_t)c * 8 * E_DIM + k0, Al + c * 512);
            gll16(bsrc + (size_t)c * 8 * E_DIM + k0, Bl + c * 512);
        }
        __syncthreads();

        #pragma unroll
        for (int ks = 0; ks < 64; ks += 32) {
            half8 af[4], bf[4];
            #pragma unroll
            for (int i = 0; i < 4; i++) {
                int row = wm * 64 + i * 16 + r;
                af[i] = *(const half8*)&Al[row * 64 + ((ks + g * 8) ^ ((row & 7) << 3))];
            }
            #pragma unroll
            for (int j = 0; j < 4; j++) {
                int row = wn * 64 + j * 16 + r;
                bf[j] = *(const half8*)&Bl[row * 64 + ((ks + g * 8) ^ ((row & 7) << 3))];
            }
            #pragma unroll
            for (int i = 0; i < 4; i++)
                #pragma unroll
                for (int j = 0; j < 4; j++)
                    acc[i][j] = MFMA16x32(af[i], bf[j], acc[i][j]);
        }
    }

    #pragma unroll
    for (int j = 0; j < 4; j++) {
        int col = ntl * 128 + wn * 64 + j * 16 + r;   // local col in [0,1024)
        float bb = bias[col];
        #pragma unroll
        for (int i = 0; i < 4; i++)
            #pragma unroll
            for (int rr = 0; rr < 4; rr++) {
                int row = m0 + wm * 64 + i * 16 + g * 4 + rr;
                out[(size_t)row * E_DIM + col] = (f16)(acc[i][j][rr] + bb);
            }
    }
}

// ---------------------------------------------------------------------------
// Kernel 1 fallback (round-4 proven): A reg-staged from f32 x, B = WT f16.
// ---------------------------------------------------------------------------
__global__ __launch_bounds__(256) void qkv_proj_v2(
    const float* __restrict__ x,
    const f16* __restrict__ WTq, const f16* __restrict__ WTk,
    const f16* __restrict__ WTv,
    const float* __restrict__ bq, const float* __restrict__ bk,
    const float* __restrict__ bv,
    f16* __restrict__ qh, f16* __restrict__ kh, f16* __restrict__ vh)
{
    const int flat = blockIdx.x;
    const int rb = (flat & 7) * 96 + (flat >> 3);
    const int nt = rb & 7;
    const int mt = (rb >> 3) & 31;
    const int z  = rb >> 8;

    const f16* WT     = (z == 0) ? WTq : (z == 1) ? WTk : WTv;
    const float* bias = (z == 0) ? bq : (z == 1) ? bk : bv;
    f16* out          = (z == 0) ? qh : (z == 1) ? kh : vh;

    const int m0 = mt * 128, n0 = nt * 128;
    const int tid = threadIdx.x;
    const int lane = tid & 63;
    const int w  = tid >> 6;
    const int wm = w >> 1, wn = w & 1;
    const int g  = lane >> 4, r = lane & 15;

    __shared__ f16 Al[128 * 32];
    __shared__ f16 Bl[128 * 32];

    floatx4 acc[4][4];
    #pragma unroll
    for (int i = 0; i < 4; i++)
        #pragma unroll
        for (int j = 0; j < 4; j++)
            acc[i][j] = (floatx4){0.f, 0.f, 0.f, 0.f};

    for (int k0 = 0; k0 < E_DIM; k0 += 32) {
        #pragma unroll
        for (int it = 0; it < 2; it++) {
            int idx = tid + it * 256;
            int mm = idx >> 2, kc = (idx & 3) * 8;
            const float* s = &x[(size_t)(m0 + mm) * E_DIM + k0 + kc];
            float4 u = *(const float4*)s;
            float4 v = *(const float4*)(s + 4);
            half8 hv = {(f16)u.x,(f16)u.y,(f16)u.z,(f16)u.w,
                        (f16)v.x,(f16)v.y,(f16)v.z,(f16)v.w};
            *(half8*)&Al[mm * 32 + (kc ^ (((mm >> 2) & 3) << 3))] = hv;
        }
        #pragma unroll
        for (int it = 0; it < 2; it++) {
            int idx = tid + it * 256;
            int nn = idx >> 2, kc = (idx & 3) * 8;
            half8 hv = *(const half8*)&WT[(size_t)(n0 + nn) * E_DIM + k0 + kc];
            *(half8*)&Bl[nn * 32 + (kc ^ (((nn >> 2) & 3) << 3))] = hv;
        }
        __syncthreads();

        half8 af[4], bf[4];
        #pragma unroll
        for (int i = 0; i < 4; i++) {
            int row = wm * 64 + i * 16 + r;
            af[i] = *(const half8*)&Al[row * 32 + ((g * 8) ^ (((row >> 2) & 3) << 3))];
        }
        #pragma unroll
        for (int j = 0; j < 4; j++) {
            int row = wn * 64 + j * 16 + r;
            bf[j] = *(const half8*)&Bl[row * 32 + ((g * 8) ^ (((row >> 2) & 3) << 3))];
        }
        #pragma unroll
        for (int i = 0; i < 4; i++)
            #pragma unroll
            for (int j = 0; j < 4; j++)
                acc[i][j] = MFMA16x32(af[i], bf[j], acc[i][j]);
        __syncthreads();
    }

    #pragma unroll
    for (int j = 0; j < 4; j++) {
        int col = n0 + wn * 64 + j * 16 + r;
        float bb = bias[col];
        #pragma unroll
        for (int i = 0; i < 4; i++)
            #pragma unroll
            for (int rr = 0; rr < 4; rr++) {
                int row = m0 + wm * 64 + i * 16 + g * 4 + rr;
                out[(size_t)row * E_DIM + col] = (f16)(acc[i][j][rr] + bb);
            }
    }
}

// ---------------------------------------------------------------------------
// Kernel 2: flash attention, swapped QK^T AND transposed PV (O^T = V^T P^T).
// Lane (g,r) owns q = qf*16 + r for softmax AND output -> no broadcasts.
// 8 waves x 32 q (2 frags), QBLK=256, grid 256, KVBLK=64, LDS 16KB.
// K staged via global_load_lds (pre-swizzled source, key (row&7));
// V stored [d][kv_perm] with paired half2v writes.
// ---------------------------------------------------------------------------
__global__ __launch_bounds__(512, 2) void attn(
    const f16* __restrict__ qh, const f16* __restrict__ kh,
    const f16* __restrict__ vh, float* __restrict__ out)
{
    const int flat = blockIdx.x;                 // 256 blocks = 8*32
    const int rb = (flat & 7) * 32 + (flat >> 3);
    const int qt = rb & 7;
    const int hh = (rb >> 3) & 15;
    const int b  = rb >> 7;
    const int q0 = qt * 256;

    const int tid = threadIdx.x;
    const int lane = tid & 63;
    const int w = tid >> 6;                      // 0..7
    const int g = lane >> 4, r = lane & 15;

    __shared__ f16 K_s[64 * 64];                 // [kv][d], key (kv&7)<<3
    __shared__ f16 V_s[64 * 64];                 // [d][kv_perm], key ((d^(d>>3))&7)<<3

    const size_t base = ((size_t)b * SEQ) * E_DIM + (size_t)hh * HDIM;

    // Q fragments: rows q0 + w*32 + qf*16 + r
    half8 aq[2][2];
    #pragma unroll
    for (int qf = 0; qf < 2; qf++) {
        const f16* qp = &qh[base + (size_t)(q0 + w * 32 + qf * 16 + r) * E_DIM];
        aq[qf][0] = *(const half8*)&qp[g * 8];
        aq[qf][1] = *(const half8*)&qp[32 + g * 8];
    }

    // K staging (global_load_lds): wave w stages rows w*8..w*8+8
    const int krow = w * 8 + (lane >> 3);
    const int kcol = ((lane & 7) ^ (lane >> 3)) * 8;        // pre-swizzled
    const f16* kg0 = kh + base + (size_t)krow * E_DIM + kcol;
    f16* klds = K_s + w * 512;

    // V staging: thread handles kv pair {2p, 2p+1} x 4 d
    const int vp = tid >> 4, vdc = (tid & 15) * 4;
    const int kv0 = vp * 2;
    const int kvp0 = (kv0 & 3) | (((kv0 >> 4) & 1) << 2) |
                     (((kv0 >> 2) & 3) << 3) | ((kv0 >> 5) << 5);
    const f16* vg0 = vh + base + (size_t)kv0 * E_DIM + vdc;

    float m_run[2] = {-1e30f, -1e30f}, l_run[2] = {0.f, 0.f};
    floatx4 acco[2][4];
    #pragma unroll
    for (int qf = 0; qf < 2; qf++)
        #pragma unroll
        for (int dj = 0; dj < 4; dj++)
            acco[qf][dj] = (floatx4){0.f, 0.f, 0.f, 0.f};

    for (int kt = 0; kt < SEQ; kt += 64) {
        if (kt) __syncthreads();
        // --- stage K (async DMA) + V (paired writes) ---
        gll16(kg0 + (size_t)kt * E_DIM, klds);
        {
            const f16* vsrc = vg0 + (size_t)kt * E_DIM;
            half4 v0 = *(const half4*)vsrc;
            half4 v1 = *(const half4*)(vsrc + E_DIM);
            #pragma unroll
            for (int e = 0; e < 4; e++) {
                int d = vdc + e;
                int swv = ((d ^ (d >> 3)) & 7) << 3;
                half2v pr = {v0[e], v1[e]};
                *(half2v*)&V_s[d * 64 + (kvp0 ^ swv)] = pr;
            }
        }
        __syncthreads();

        // --- S^T = K Q^T : lane (g,r): sct[qf][kb][rr] = S[q=qf*16+r][kv=kb*16+g*4+rr]
        floatx4 sct[2][4];
        #pragma unroll
        for (int qf = 0; qf < 2; qf++)
            #pragma unroll
            for (int kb = 0; kb < 4; kb++)
                sct[qf][kb] = (floatx4){0.f, 0.f, 0.f, 0.f};
        #pragma unroll
        for (int kb = 0; kb < 4; kb++) {
            int kr2 = kb * 16 + r;
            int swk = (kr2 & 7) << 3;
            const f16* kb_ = &K_s[kr2 * 64];
            half8 kf0 = *(const half8*)&kb_[(g * 8) ^ swk];
            half8 kf1 = *(const half8*)&kb_[(32 + g * 8) ^ swk];
            #pragma unroll
            for (int qf = 0; qf < 2; qf++) {
                sct[qf][kb] = MFMA16x32(kf0, aq[qf][0], sct[qf][kb]);
                sct[qf][kb] = MFMA16x32(kf1, aq[qf][1], sct[qf][kb]);
            }
        }

        // --- online softmax, fully lane-local per q=qf*16+r ---
        half8 pa[2][2];
        #pragma unroll
        for (int qf = 0; qf < 2; qf++) {
            float pm = sct[qf][0][0];
            #pragma unroll
            for (int kb = 0; kb < 4; kb++)
                #pragma unroll
                for (int rr = 0; rr < 4; rr++)
                    pm = fmaxf(pm, sct[qf][kb][rr]);
            pm = fmaxf(pm, __shfl_xor(pm, 16, 64));
            pm = fmaxf(pm, __shfl_xor(pm, 32, 64));
            float mn = fmaxf(m_run[qf], pm);
            float alpha = __expf(m_run[qf] - mn);
            m_run[qf] = mn;
            float rs = 0.f;
            #pragma unroll
            for (int kb = 0; kb < 4; kb++)
                #pragma unroll
                for (int rr = 0; rr < 4; rr++) {
                    float e = __expf(sct[qf][kb][rr] - mn);
                    sct[qf][kb][rr] = e;
                    rs += e;
                }
            rs += __shfl_xor(rs, 16, 64);
            rs += __shfl_xor(rs, 32, 64);
            l_run[qf] = l_run[qf] * alpha + rs;
            #pragma unroll
            for (int dj = 0; dj < 4; dj++)
                #pragma unroll
                for (int rr = 0; rr < 4; rr++)
                    acco[qf][dj][rr] *= alpha;
            // pack P: pa[qf][h] slot (u*4+c) = P[q][kv=(h*2+u)*16+g*4+c]
            #pragma unroll
            for (int h = 0; h < 2; h++) {
                half8 t = {(f16)sct[qf][h*2][0],   (f16)sct[qf][h*2][1],
                           (f16)sct[qf][h*2][2],   (f16)sct[qf][h*2][3],
                           (f16)sct[qf][h*2+1][0], (f16)sct[qf][h*2+1][1],
                           (f16)sct[qf][h*2+1][2], (f16)sct[qf][h*2+1][3]};
                pa[qf][h] = t;
            }
        }

        // --- O^T += V^T P^T : A = V^T frag (rows d), B = P frag ---
        #pragma unroll
        for (int dj = 0; dj < 4; dj++) {
            int d = dj * 16 + r;
            int swv = ((d ^ (d >> 3)) & 7) << 3;
            const f16* vb_ = &V_s[d * 64];
            half8 vf0 = *(const half8*)&vb_[(g * 8) ^ swv];
            half8 vf1 = *(const half8*)&vb_[(32 + g * 8) ^ swv];
            #pragma unroll
            for (int qf = 0; qf < 2; qf++) {
                acco[qf][dj] = MFMA16x32(vf0, pa[qf][0], acco[qf][dj]);
                acco[qf][dj] = MFMA16x32(vf1, pa[qf][1], acco[qf][dj]);
            }
        }
    }

    // --- epilogue: acco[qf][dj][rr] = O[q=qf*16+r][d=dj*16+g*4+rr] ---
    #pragma unroll
    for (int qf = 0; qf < 2; qf++) {
        float inv = 1.f / l_run[qf];
        int row = q0 + w * 32 + qf * 16 + r;
        float* orow = out + (size_t)(b * SEQ + row) * E_DIM + hh * HDIM;
        #pragma unroll
        for (int dj = 0; dj < 4; dj++) {
            float4 st = {acco[qf][dj][0] * inv, acco[qf][dj][1] * inv,
                         acco[qf][dj][2] * inv, acco[qf][dj][3] * inv};
            *(float4*)&orow[dj * 16 + g * 4] = st;
        }
    }
}

extern "C" void kernel_launch(void* const* d_in, const int* in_sizes, int n_in,
                              void* d_out, int out_size, void* d_ws, size_t ws_size,
                              hipStream_t stream) {
    const float* x  = (const float*)d_in[0];
    const float* Wq = (const float*)d_in[1];
    const float* bq = (const float*)d_in[2];
    const float* Wk = (const float*)d_in[3];
    const float* bk = (const float*)d_in[4];
    const float* Wv = (const float*)d_in[5];
    const float* bv = (const float*)d_in[6];
    float* out = (float*)d_out;

    const size_t qkv_elems = (size_t)M_TOT * E_DIM;          // 4M f16 each
    const size_t w_elems   = (size_t)E_DIM * E_DIM;          // 1M f16 each
    f16* qh  = (f16*)d_ws;
    f16* kh  = qh + qkv_elems;
    f16* vh  = kh + qkv_elems;
    f16* WTq = vh + qkv_elems;        // WTq/WTk/WTv contiguous = WTall
    f16* WTk = WTq + w_elems;
    f16* WTv = WTk + w_elems;
    f16* xh  = WTv + w_elems;
    const size_t need_v3  = (3 * qkv_elems + 3 * w_elems + qkv_elems) * sizeof(f16); // 38 MB
    const size_t need_v2  = (3 * qkv_elems + 3 * w_elems) * sizeof(f16);             // 30 MB
    if (ws_size < need_v2) return;

    if (ws_size >= need_v3) {
        cvt_x<<<dim3(M_TOT * E_DIM / (256 * 8)), 256, 0, stream>>>(x, xh);
        transpose_w<<<dim3(16, 16, 3), 256, 0, stream>>>(Wq, Wk, Wv, WTq, WTk, WTv);
        qkv_gemm<<<dim3((E_DIM / 128) * (M_TOT / 128) * 3), 256, 0, stream>>>(
            xh, WTq, bq, bk, bv, qh, kh, vh);
    } else {
        transpose_w<<<dim3(16, 16, 3), 256, 0, stream>>>(Wq, Wk, Wv, WTq, WTk, WTv);
        qkv_proj_v2<<<dim3((E_DIM / 128) * (M_TOT / 128) * 3), 256, 0, stream>>>(
            x, WTq, WTk, WTv, bq, bk, bv, qh, kh, vh);
    }
    attn<<<dim3((SEQ / 256) * NHEADS * BATCH), 512, 0, stream>>>(qh, kh, vh, out);
}

// Round 6
// 173.489 us; speedup vs baseline: 2.3261x; 1.0559x over previous
//
#include <hip/hip_runtime.h>

#define E_DIM 1024
#define NHEADS 16
#define HDIM 64
#define BATCH 2
#define SEQ 2048
#define M_TOT (BATCH*SEQ)   // 4096

typedef _Float16 f16;
typedef _Float16 half4 __attribute__((ext_vector_type(4)));
typedef _Float16 half8 __attribute__((ext_vector_type(8)));
typedef _Float16 half2v __attribute__((ext_vector_type(2)));
typedef float floatx4 __attribute__((ext_vector_type(4)));

#define MFMA16x32(a,b,c) __builtin_amdgcn_mfma_f32_16x16x32_f16((a),(b),(c),0,0,0)

// async global->LDS, 16B per lane, LDS dest = wave-uniform base + lane*16
__device__ __forceinline__ void gll16(const f16* gsrc, f16* ldst) {
    __builtin_amdgcn_global_load_lds(
        (const __attribute__((address_space(1))) void*)gsrc,
        (__attribute__((address_space(3))) void*)ldst, 16, 0, 0);
}

// ---------------------------------------------------------------------------
// Prep A: x f32 -> f16
// ---------------------------------------------------------------------------
__global__ __launch_bounds__(256) void cvt_x(const float* __restrict__ x,
                                             f16* __restrict__ xh) {
    size_t i = ((size_t)blockIdx.x * 256 + threadIdx.x) * 8;
    float4 a = *(const float4*)&x[i];
    float4 b = *(const float4*)&x[i + 4];
    half8 h = {(f16)a.x,(f16)a.y,(f16)a.z,(f16)a.w,
               (f16)b.x,(f16)b.y,(f16)b.z,(f16)b.w};
    *(half8*)&xh[i] = h;
}

// ---------------------------------------------------------------------------
// Prep B: W [k][n] f32 -> WT [n][k] f16 (64x64 tiles, LDS bounce)
// ---------------------------------------------------------------------------
__global__ __launch_bounds__(256) void transpose_w(
    const float* __restrict__ Wq, const float* __restrict__ Wk,
    const float* __restrict__ Wv,
    f16* __restrict__ WTq, f16* __restrict__ WTk, f16* __restrict__ WTv)
{
    const int z = blockIdx.z;
    const float* W = (z == 0) ? Wq : (z == 1) ? Wk : Wv;
    f16* WT        = (z == 0) ? WTq : (z == 1) ? WTk : WTv;

    const int k0 = blockIdx.x * 64, n0 = blockIdx.y * 64;
    const int tid = threadIdx.x;
    __shared__ f16 T[64][68];

    {
        const int tr = tid >> 4, tc = tid & 15;
        float4 f4[4];
        #pragma unroll
        for (int i = 0; i < 4; i++)
            f4[i] = *(const float4*)&W[(size_t)(k0 + tr * 4 + i) * E_DIM + n0 + tc * 4];
        #pragma unroll
        for (int j = 0; j < 4; j++) {
            float e0 = (j==0)?f4[0].x:(j==1)?f4[0].y:(j==2)?f4[0].z:f4[0].w;
            float e1 = (j==0)?f4[1].x:(j==1)?f4[1].y:(j==2)?f4[1].z:f4[1].w;
            float e2 = (j==0)?f4[2].x:(j==1)?f4[2].y:(j==2)?f4[2].z:f4[2].w;
            float e3 = (j==0)?f4[3].x:(j==1)?f4[3].y:(j==2)?f4[3].z:f4[3].w;
            half4 h = {(f16)e0, (f16)e1, (f16)e2, (f16)e3};
            *(half4*)&T[tc * 4 + j][tr * 4] = h;
        }
    }
    __syncthreads();
    {
        const int nn = tid >> 2, kk = (tid & 3) * 16;
        half8 a = *(const half8*)&T[nn][kk];
        half8 b = *(const half8*)&T[nn][kk + 8];
        f16* dst = &WT[(size_t)(n0 + nn) * E_DIM + k0 + kk];
        *(half8*)dst = a;
        *(half8*)(dst + 8) = b;
    }
}

// ---------------------------------------------------------------------------
// Kernel 1 v3: pure-f16 GEMM, m97 structure (unchanged from round 5).
// ---------------------------------------------------------------------------
__global__ __launch_bounds__(256) void qkv_gemm(
    const f16* __restrict__ xh, const f16* __restrict__ WTall,
    const float* __restrict__ bq, const float* __restrict__ bk,
    const float* __restrict__ bv,
    f16* __restrict__ qh, f16* __restrict__ kh, f16* __restrict__ vh)
{
    const int flat = blockIdx.x;                  // 768 = 8*96
    const int rb = (flat & 7) * 96 + (flat >> 3);
    const int z   = rb >> 8;
    const int ntl = rb & 7;
    const int mt  = (rb >> 3) & 31;

    const float* bias = (z == 0) ? bq : (z == 1) ? bk : bv;
    f16* out          = (z == 0) ? qh : (z == 1) ? kh : vh;

    const int m0 = mt * 128;
    const int n0g = z * 1024 + ntl * 128;
    const int tid = threadIdx.x;
    const int lane = tid & 63;
    const int w  = tid >> 6;
    const int wm = w >> 1, wn = w & 1;
    const int g  = lane >> 4, r = lane & 15;

    __shared__ f16 Al[128 * 64];
    __shared__ f16 Bl[128 * 64];

    const int lrow = lane >> 3;
    const int lcol = ((lane & 7) ^ lrow) * 8;
    const f16* asrc = xh    + (size_t)(m0  + lrow) * E_DIM + lcol;
    const f16* bsrc = WTall + (size_t)(n0g + lrow) * E_DIM + lcol;

    floatx4 acc[4][4];
    #pragma unroll
    for (int i = 0; i < 4; i++)
        #pragma unroll
        for (int j = 0; j < 4; j++)
            acc[i][j] = (floatx4){0.f, 0.f, 0.f, 0.f};

    for (int k0 = 0; k0 < E_DIM; k0 += 64) {
        if (k0) __syncthreads();
        #pragma unroll
        for (int t = 0; t < 4; t++) {
            int c = w * 4 + t;
            gll16(asrc + (size_t)c * 8 * E_DIM + k0, Al + c * 512);
            gll16(bsrc + (size_t)c * 8 * E_DIM + k0, Bl + c * 512);
        }
        __syncthreads();

        #pragma unroll
        for (int ks = 0; ks < 64; ks += 32) {
            half8 af[4], bf[4];
            #pragma unroll
            for (int i = 0; i < 4; i++) {
                int row = wm * 64 + i * 16 + r;
                af[i] = *(const half8*)&Al[row * 64 + ((ks + g * 8) ^ ((row & 7) << 3))];
            }
            #pragma unroll
            for (int j = 0; j < 4; j++) {
                int row = wn * 64 + j * 16 + r;
                bf[j] = *(const half8*)&Bl[row * 64 + ((ks + g * 8) ^ ((row & 7) << 3))];
            }
            #pragma unroll
            for (int i = 0; i < 4; i++)
                #pragma unroll
                for (int j = 0; j < 4; j++)
                    acc[i][j] = MFMA16x32(af[i], bf[j], acc[i][j]);
        }
    }

    #pragma unroll
    for (int j = 0; j < 4; j++) {
        int col = ntl * 128 + wn * 64 + j * 16 + r;
        float bb = bias[col];
        #pragma unroll
        for (int i = 0; i < 4; i++)
            #pragma unroll
            for (int rr = 0; rr < 4; rr++) {
                int row = m0 + wm * 64 + i * 16 + g * 4 + rr;
                out[(size_t)row * E_DIM + col] = (f16)(acc[i][j][rr] + bb);
            }
    }
}

// ---------------------------------------------------------------------------
// Kernel 1 fallback (round-4 proven)
// ---------------------------------------------------------------------------
__global__ __launch_bounds__(256) void qkv_proj_v2(
    const float* __restrict__ x,
    const f16* __restrict__ WTq, const f16* __restrict__ WTk,
    const f16* __restrict__ WTv,
    const float* __restrict__ bq, const float* __restrict__ bk,
    const float* __restrict__ bv,
    f16* __restrict__ qh, f16* __restrict__ kh, f16* __restrict__ vh)
{
    const int flat = blockIdx.x;
    const int rb = (flat & 7) * 96 + (flat >> 3);
    const int nt = rb & 7;
    const int mt = (rb >> 3) & 31;
    const int z  = rb >> 8;

    const f16* WT     = (z == 0) ? WTq : (z == 1) ? WTk : WTv;
    const float* bias = (z == 0) ? bq : (z == 1) ? bk : bv;
    f16* out          = (z == 0) ? qh : (z == 1) ? kh : vh;

    const int m0 = mt * 128, n0 = nt * 128;
    const int tid = threadIdx.x;
    const int lane = tid & 63;
    const int w  = tid >> 6;
    const int wm = w >> 1, wn = w & 1;
    const int g  = lane >> 4, r = lane & 15;

    __shared__ f16 Al[128 * 32];
    __shared__ f16 Bl[128 * 32];

    floatx4 acc[4][4];
    #pragma unroll
    for (int i = 0; i < 4; i++)
        #pragma unroll
        for (int j = 0; j < 4; j++)
            acc[i][j] = (floatx4){0.f, 0.f, 0.f, 0.f};

    for (int k0 = 0; k0 < E_DIM; k0 += 32) {
        #pragma unroll
        for (int it = 0; it < 2; it++) {
            int idx = tid + it * 256;
            int mm = idx >> 2, kc = (idx & 3) * 8;
            const float* s = &x[(size_t)(m0 + mm) * E_DIM + k0 + kc];
            float4 u = *(const float4*)s;
            float4 v = *(const float4*)(s + 4);
            half8 hv = {(f16)u.x,(f16)u.y,(f16)u.z,(f16)u.w,
                        (f16)v.x,(f16)v.y,(f16)v.z,(f16)v.w};
            *(half8*)&Al[mm * 32 + (kc ^ (((mm >> 2) & 3) << 3))] = hv;
        }
        #pragma unroll
        for (int it = 0; it < 2; it++) {
            int idx = tid + it * 256;
            int nn = idx >> 2, kc = (idx & 3) * 8;
            half8 hv = *(const half8*)&WT[(size_t)(n0 + nn) * E_DIM + k0 + kc];
            *(half8*)&Bl[nn * 32 + (kc ^ (((nn >> 2) & 3) << 3))] = hv;
        }
        __syncthreads();

        half8 af[4], bf[4];
        #pragma unroll
        for (int i = 0; i < 4; i++) {
            int row = wm * 64 + i * 16 + r;
            af[i] = *(const half8*)&Al[row * 32 + ((g * 8) ^ (((row >> 2) & 3) << 3))];
        }
        #pragma unroll
        for (int j = 0; j < 4; j++) {
            int row = wn * 64 + j * 16 + r;
            bf[j] = *(const half8*)&Bl[row * 32 + ((g * 8) ^ (((row >> 2) & 3) << 3))];
        }
        #pragma unroll
        for (int i = 0; i < 4; i++)
            #pragma unroll
            for (int j = 0; j < 4; j++)
                acc[i][j] = MFMA16x32(af[i], bf[j], acc[i][j]);
        __syncthreads();
    }

    #pragma unroll
    for (int j = 0; j < 4; j++) {
        int col = n0 + wn * 64 + j * 16 + r;
        float bb = bias[col];
        #pragma unroll
        for (int i = 0; i < 4; i++)
            #pragma unroll
            for (int rr = 0; rr < 4; rr++) {
                int row = m0 + wm * 64 + i * 16 + g * 4 + rr;
                out[(size_t)row * E_DIM + col] = (f16)(acc[i][j][rr] + bb);
            }
    }
}

// ---------------------------------------------------------------------------
// Kernel 2: flash attention. Swapped QK^T + transposed PV (all lane-local).
// QBLK=128, 8 waves x 16 q-rows, grid 512 (2 blocks/CU), KVBLK=64.
// Double-buffered K/V (32KB LDS), prefetch issued before compute (2-phase),
// defer-max rescale (THR=8), setprio around MFMA clusters.
// ---------------------------------------------------------------------------
__global__ __launch_bounds__(512, 4) void attn(
    const f16* __restrict__ qh, const f16* __restrict__ kh,
    const f16* __restrict__ vh, float* __restrict__ out)
{
    const int flat = blockIdx.x;                 // 512 blocks = 8*64
    const int rb = (flat & 7) * 64 + (flat >> 3);
    const int qt = rb & 15;
    const int hh = (rb >> 4) & 15;
    const int b  = rb >> 8;
    const int q0 = qt * 128;

    const int tid = threadIdx.x;
    const int lane = tid & 63;
    const int w = tid >> 6;                      // 0..7
    const int g = lane >> 4, r = lane & 15;

    __shared__ f16 K_s[2][64 * 64];              // [kv][d], key (kv&7)<<3
    __shared__ f16 V_s[2][64 * 64];              // [d][kv_perm], key ((d^(d>>3))&7)<<3

    const size_t base = ((size_t)b * SEQ) * E_DIM + (size_t)hh * HDIM;

    // Q fragment: row q0 + w*16 + r
    half8 aq[2];
    {
        const f16* qp = &qh[base + (size_t)(q0 + w * 16 + r) * E_DIM];
        aq[0] = *(const half8*)&qp[g * 8];
        aq[1] = *(const half8*)&qp[32 + g * 8];
    }

    // K staging: wave w stages rows w*8..w*8+8, pre-swizzled source col
    const int klrow = lane >> 3;
    const int kcol = ((lane & 7) ^ klrow) * 8;
    const f16* kg0 = kh + base + (size_t)(w * 8 + klrow) * E_DIM + kcol;

    // V staging: thread handles kv pair {2p,2p+1} x 4 d
    const int vp = tid >> 4, vdc = (tid & 15) * 4;
    const int kv0 = vp * 2;
    const int kvp0 = (kv0 & 3) | (((kv0 >> 4) & 1) << 2) |
                     (((kv0 >> 2) & 3) << 3) | ((kv0 >> 5) << 5);
    const f16* vg0 = vh + base + (size_t)kv0 * E_DIM + vdc;

    float m_run = -1e30f, l_run = 0.f;
    floatx4 acco[4];
    #pragma unroll
    for (int dj = 0; dj < 4; dj++) acco[dj] = (floatx4){0.f, 0.f, 0.f, 0.f};

    const int NT = SEQ / 64;

    // --- prologue: stage tile 0 into buffer 0 ---
    gll16(kg0, &K_s[0][w * 512]);
    {
        half4 v0 = *(const half4*)vg0;
        half4 v1 = *(const half4*)(vg0 + E_DIM);
        #pragma unroll
        for (int e = 0; e < 4; e++) {
            int d = vdc + e;
            int swv = ((d ^ (d >> 3)) & 7) << 3;
            half2v pr = {v0[e], v1[e]};
            *(half2v*)&V_s[0][d * 64 + (kvp0 ^ swv)] = pr;
        }
    }
    __syncthreads();

    for (int t = 0; t < NT; t++) {
        const int cur = t & 1;
        const bool pf = (t + 1 < NT);
        half4 v0n, v1n;
        if (pf) {
            // issue next-tile loads: K via async DMA, V to regs
            gll16(kg0 + (size_t)(t + 1) * 64 * E_DIM, &K_s[cur ^ 1][w * 512]);
            const f16* vsrc = vg0 + (size_t)(t + 1) * 64 * E_DIM;
            v0n = *(const half4*)vsrc;
            v1n = *(const half4*)(vsrc + E_DIM);
        }

        // --- S^T = K Q^T : lane (g,r): sct[kb][rr] = S[q=r][kv=kb*16+g*4+rr]
        floatx4 sct[4];
        __builtin_amdgcn_s_setprio(1);
        #pragma unroll
        for (int kb = 0; kb < 4; kb++) {
            int kr2 = kb * 16 + r;
            int swk = (kr2 & 7) << 3;
            const f16* kb_ = &K_s[cur][kr2 * 64];
            half8 kf0 = *(const half8*)&kb_[(g * 8) ^ swk];
            half8 kf1 = *(const half8*)&kb_[(32 + g * 8) ^ swk];
            floatx4 c = (floatx4){0.f, 0.f, 0.f, 0.f};
            c = MFMA16x32(kf0, aq[0], c);
            c = MFMA16x32(kf1, aq[1], c);
            sct[kb] = c;
        }
        __builtin_amdgcn_s_setprio(0);

        // --- online softmax, lane-local (q = r), defer-max THR=8 ---
        float pm = sct[0][0];
        #pragma unroll
        for (int kb = 0; kb < 4; kb++)
            #pragma unroll
            for (int rr = 0; rr < 4; rr++)
                pm = fmaxf(pm, sct[kb][rr]);
        pm = fmaxf(pm, __shfl_xor(pm, 16, 64));
        pm = fmaxf(pm, __shfl_xor(pm, 32, 64));
        if (!__all(pm - m_run <= 8.f)) {
            float mn = fmaxf(m_run, pm);
            float alpha = __expf(m_run - mn);
            m_run = mn;
            l_run *= alpha;
            #pragma unroll
            for (int dj = 0; dj < 4; dj++)
                #pragma unroll
                for (int rr = 0; rr < 4; rr++)
                    acco[dj][rr] *= alpha;
        }
        float rs = 0.f;
        #pragma unroll
        for (int kb = 0; kb < 4; kb++)
            #pragma unroll
            for (int rr = 0; rr < 4; rr++) {
                float e = __expf(sct[kb][rr] - m_run);
                sct[kb][rr] = e;
                rs += e;
            }
        rs += __shfl_xor(rs, 16, 64);
        rs += __shfl_xor(rs, 32, 64);
        l_run += rs;

        // pack P: pa[h] slot (u*4+c) = P[q][kv=(h*2+u)*16+g*4+c]
        half8 pa[2];
        #pragma unroll
        for (int h = 0; h < 2; h++) {
            half8 tv = {(f16)sct[h*2][0],   (f16)sct[h*2][1],
                        (f16)sct[h*2][2],   (f16)sct[h*2][3],
                        (f16)sct[h*2+1][0], (f16)sct[h*2+1][1],
                        (f16)sct[h*2+1][2], (f16)sct[h*2+1][3]};
            pa[h] = tv;
        }

        // --- write prefetched V into next buffer (latency hidden by above) ---
        if (pf) {
            #pragma unroll
            for (int e = 0; e < 4; e++) {
                int d = vdc + e;
                int swv = ((d ^ (d >> 3)) & 7) << 3;
                half2v pr = {v0n[e], v1n[e]};
                *(half2v*)&V_s[cur ^ 1][d * 64 + (kvp0 ^ swv)] = pr;
            }
        }

        // --- O^T += V^T P^T ---
        __builtin_amdgcn_s_setprio(1);
        #pragma unroll
        for (int dj = 0; dj < 4; dj++) {
            int d = dj * 16 + r;
            int swv = ((d ^ (d >> 3)) & 7) << 3;
            const f16* vb_ = &V_s[cur][d * 64];
            half8 vf0 = *(const half8*)&vb_[(g * 8) ^ swv];
            half8 vf1 = *(const half8*)&vb_[(32 + g * 8) ^ swv];
            acco[dj] = MFMA16x32(vf0, pa[0], acco[dj]);
            acco[dj] = MFMA16x32(vf1, pa[1], acco[dj]);
        }
        __builtin_amdgcn_s_setprio(0);

        __syncthreads();   // next tile's buffers ready; this tile's reads done
    }

    // --- epilogue: acco[dj][rr] = O[q=r][d=dj*16+g*4+rr] ---
    {
        float inv = 1.f / l_run;
        int row = q0 + w * 16 + r;
        float* orow = out + (size_t)(b * SEQ + row) * E_DIM + hh * HDIM;
        #pragma unroll
        for (int dj = 0; dj < 4; dj++) {
            float4 st = {acco[dj][0] * inv, acco[dj][1] * inv,
                         acco[dj][2] * inv, acco[dj][3] * inv};
            *(float4*)&orow[dj * 16 + g * 4] = st;
        }
    }
}

extern "C" void kernel_launch(void* const* d_in, const int* in_sizes, int n_in,
                              void* d_out, int out_size, void* d_ws, size_t ws_size,
                              hipStream_t stream) {
    const float* x  = (const float*)d_in[0];
    const float* Wq = (const float*)d_in[1];
    const float* bq = (const float*)d_in[2];
    const float* Wk = (const float*)d_in[3];
    const float* bk = (const float*)d_in[4];
    const float* Wv = (const float*)d_in[5];
    const float* bv = (const float*)d_in[6];
    float* out = (float*)d_out;

    const size_t qkv_elems = (size_t)M_TOT * E_DIM;          // 4M f16 each
    const size_t w_elems   = (size_t)E_DIM * E_DIM;          // 1M f16 each
    f16* qh  = (f16*)d_ws;
    f16* kh  = qh + qkv_elems;
    f16* vh  = kh + qkv_elems;
    f16* WTq = vh + qkv_elems;        // WTq/WTk/WTv contiguous = WTall
    f16* WTk = WTq + w_elems;
    f16* WTv = WTk + w_elems;
    f16* xh  = WTv + w_elems;
    const size_t need_v3  = (3 * qkv_elems + 3 * w_elems + qkv_elems) * sizeof(f16); // 38 MB
    const size_t need_v2  = (3 * qkv_elems + 3 * w_elems) * sizeof(f16);             // 30 MB
    if (ws_size < need_v2) return;

    if (ws_size >= need_v3) {
        cvt_x<<<dim3(M_TOT * E_DIM / (256 * 8)), 256, 0, stream>>>(x, xh);
        transpose_w<<<dim3(16, 16, 3), 256, 0, stream>>>(Wq, Wk, Wv, WTq, WTk, WTv);
        qkv_gemm<<<dim3((E_DIM / 128) * (M_TOT / 128) * 3), 256, 0, stream>>>(
            xh, WTq, bq, bk, bv, qh, kh, vh);
    } else {
        transpose_w<<<dim3(16, 16, 3), 256, 0, stream>>>(Wq, Wk, Wv, WTq, WTk, WTv);
        qkv_proj_v2<<<dim3((E_DIM / 128) * (M_TOT / 128) * 3), 256, 0, stream>>>(
            x, WTq, WTk, WTv, bq, bk, bv, qh, kh, vh);
    }
    attn<<<dim3((SEQ / 128) * NHEADS * BATCH), 512, 0, stream>>>(qh, kh, vh, out);
}

// Round 8
// 169.123 us; speedup vs baseline: 2.3861x; 1.0258x over previous
//
#include <hip/hip_runtime.h>

#define E_DIM 1024
#define NHEADS 16
#define HDIM 64
#define BATCH 2
#define SEQ 2048
#define M_TOT (BATCH*SEQ)   // 4096

typedef _Float16 f16;
typedef _Float16 half4 __attribute__((ext_vector_type(4)));
typedef _Float16 half8 __attribute__((ext_vector_type(8)));
typedef _Float16 half2v __attribute__((ext_vector_type(2)));
typedef float floatx4 __attribute__((ext_vector_type(4)));

#define MFMA16x32(a,b,c) __builtin_amdgcn_mfma_f32_16x16x32_f16((a),(b),(c),0,0,0)
#define EXP2F(x) __builtin_amdgcn_exp2f(x)
#define FMAX3(a,b,c) fmaxf(fmaxf((a),(b)),(c))

// cvt_pkrtz returns __fp16x2; bit-cast to our _Float16x2
__device__ __forceinline__ half2v pkrtz(float a, float b) {
    return __builtin_bit_cast(half2v, __builtin_amdgcn_cvt_pkrtz(a, b));
}

// async global->LDS, 16B per lane, LDS dest = wave-uniform base + lane*16
__device__ __forceinline__ void gll16(const f16* gsrc, f16* ldst) {
    __builtin_amdgcn_global_load_lds(
        (const __attribute__((address_space(1))) void*)gsrc,
        (__attribute__((address_space(3))) void*)ldst, 16, 0, 0);
}

// ---------------------------------------------------------------------------
// Prep A: x f32 -> f16
// ---------------------------------------------------------------------------
__global__ __launch_bounds__(256) void cvt_x(const float* __restrict__ x,
                                             f16* __restrict__ xh) {
    size_t i = ((size_t)blockIdx.x * 256 + threadIdx.x) * 8;
    float4 a = *(const float4*)&x[i];
    float4 b = *(const float4*)&x[i + 4];
    half8 h = {(f16)a.x,(f16)a.y,(f16)a.z,(f16)a.w,
               (f16)b.x,(f16)b.y,(f16)b.z,(f16)b.w};
    *(half8*)&xh[i] = h;
}

// ---------------------------------------------------------------------------
// Prep B: W [k][n] f32 -> WT [n][k] f16 (64x64 tiles, LDS bounce)
// ---------------------------------------------------------------------------
__global__ __launch_bounds__(256) void transpose_w(
    const float* __restrict__ Wq, const float* __restrict__ Wk,
    const float* __restrict__ Wv,
    f16* __restrict__ WTq, f16* __restrict__ WTk, f16* __restrict__ WTv)
{
    const int z = blockIdx.z;
    const float* W = (z == 0) ? Wq : (z == 1) ? Wk : Wv;
    f16* WT        = (z == 0) ? WTq : (z == 1) ? WTk : WTv;

    const int k0 = blockIdx.x * 64, n0 = blockIdx.y * 64;
    const int tid = threadIdx.x;
    __shared__ f16 T[64][68];

    {
        const int tr = tid >> 4, tc = tid & 15;
        float4 f4[4];
        #pragma unroll
        for (int i = 0; i < 4; i++)
            f4[i] = *(const float4*)&W[(size_t)(k0 + tr * 4 + i) * E_DIM + n0 + tc * 4];
        #pragma unroll
        for (int j = 0; j < 4; j++) {
            float e0 = (j==0)?f4[0].x:(j==1)?f4[0].y:(j==2)?f4[0].z:f4[0].w;
            float e1 = (j==0)?f4[1].x:(j==1)?f4[1].y:(j==2)?f4[1].z:f4[1].w;
            float e2 = (j==0)?f4[2].x:(j==1)?f4[2].y:(j==2)?f4[2].z:f4[2].w;
            float e3 = (j==0)?f4[3].x:(j==1)?f4[3].y:(j==2)?f4[3].z:f4[3].w;
            half4 h = {(f16)e0, (f16)e1, (f16)e2, (f16)e3};
            *(half4*)&T[tc * 4 + j][tr * 4] = h;
        }
    }
    __syncthreads();
    {
        const int nn = tid >> 2, kk = (tid & 3) * 16;
        half8 a = *(const half8*)&T[nn][kk];
        half8 b = *(const half8*)&T[nn][kk + 8];
        f16* dst = &WT[(size_t)(n0 + nn) * E_DIM + k0 + kk];
        *(half8*)dst = a;
        *(half8*)(dst + 8) = b;
    }
}

// ---------------------------------------------------------------------------
// Kernel 1 v3: pure-f16 GEMM, m97 structure (unchanged).
// ---------------------------------------------------------------------------
__global__ __launch_bounds__(256) void qkv_gemm(
    const f16* __restrict__ xh, const f16* __restrict__ WTall,
    const float* __restrict__ bq, const float* __restrict__ bk,
    const float* __restrict__ bv,
    f16* __restrict__ qh, f16* __restrict__ kh, f16* __restrict__ vh)
{
    const int flat = blockIdx.x;                  // 768 = 8*96
    const int rb = (flat & 7) * 96 + (flat >> 3);
    const int z   = rb >> 8;
    const int ntl = rb & 7;
    const int mt  = (rb >> 3) & 31;

    const float* bias = (z == 0) ? bq : (z == 1) ? bk : bv;
    f16* out          = (z == 0) ? qh : (z == 1) ? kh : vh;

    const int m0 = mt * 128;
    const int n0g = z * 1024 + ntl * 128;
    const int tid = threadIdx.x;
    const int lane = tid & 63;
    const int w  = tid >> 6;
    const int wm = w >> 1, wn = w & 1;
    const int g  = lane >> 4, r = lane & 15;

    __shared__ f16 Al[128 * 64];
    __shared__ f16 Bl[128 * 64];

    const int lrow = lane >> 3;
    const int lcol = ((lane & 7) ^ lrow) * 8;
    const f16* asrc = xh    + (size_t)(m0  + lrow) * E_DIM + lcol;
    const f16* bsrc = WTall + (size_t)(n0g + lrow) * E_DIM + lcol;

    floatx4 acc[4][4];
    #pragma unroll
    for (int i = 0; i < 4; i++)
        #pragma unroll
        for (int j = 0; j < 4; j++)
            acc[i][j] = (floatx4){0.f, 0.f, 0.f, 0.f};

    for (int k0 = 0; k0 < E_DIM; k0 += 64) {
        if (k0) __syncthreads();
        #pragma unroll
        for (int t = 0; t < 4; t++) {
            int c = w * 4 + t;
            gll16(asrc + (size_t)c * 8 * E_DIM + k0, Al + c * 512);
            gll16(bsrc + (size_t)c * 8 * E_DIM + k0, Bl + c * 512);
        }
        __syncthreads();

        #pragma unroll
        for (int ks = 0; ks < 64; ks += 32) {
            half8 af[4], bf[4];
            #pragma unroll
            for (int i = 0; i < 4; i++) {
                int row = wm * 64 + i * 16 + r;
                af[i] = *(const half8*)&Al[row * 64 + ((ks + g * 8) ^ ((row & 7) << 3))];
            }
            #pragma unroll
            for (int j = 0; j < 4; j++) {
                int row = wn * 64 + j * 16 + r;
                bf[j] = *(const half8*)&Bl[row * 64 + ((ks + g * 8) ^ ((row & 7) << 3))];
            }
            #pragma unroll
            for (int i = 0; i < 4; i++)
                #pragma unroll
                for (int j = 0; j < 4; j++)
                    acc[i][j] = MFMA16x32(af[i], bf[j], acc[i][j]);
        }
    }

    #pragma unroll
    for (int j = 0; j < 4; j++) {
        int col = ntl * 128 + wn * 64 + j * 16 + r;
        float bb = bias[col];
        #pragma unroll
        for (int i = 0; i < 4; i++)
            #pragma unroll
            for (int rr = 0; rr < 4; rr++) {
                int row = m0 + wm * 64 + i * 16 + g * 4 + rr;
                out[(size_t)row * E_DIM + col] = (f16)(acc[i][j][rr] + bb);
            }
    }
}

// ---------------------------------------------------------------------------
// Kernel 1 fallback (round-4 proven)
// ---------------------------------------------------------------------------
__global__ __launch_bounds__(256) void qkv_proj_v2(
    const float* __restrict__ x,
    const f16* __restrict__ WTq, const f16* __restrict__ WTk,
    const f16* __restrict__ WTv,
    const float* __restrict__ bq, const float* __restrict__ bk,
    const float* __restrict__ bv,
    f16* __restrict__ qh, f16* __restrict__ kh, f16* __restrict__ vh)
{
    const int flat = blockIdx.x;
    const int rb = (flat & 7) * 96 + (flat >> 3);
    const int nt = rb & 7;
    const int mt = (rb >> 3) & 31;
    const int z  = rb >> 8;

    const f16* WT     = (z == 0) ? WTq : (z == 1) ? WTk : WTv;
    const float* bias = (z == 0) ? bq : (z == 1) ? bk : bv;
    f16* out          = (z == 0) ? qh : (z == 1) ? kh : vh;

    const int m0 = mt * 128, n0 = nt * 128;
    const int tid = threadIdx.x;
    const int lane = tid & 63;
    const int w  = tid >> 6;
    const int wm = w >> 1, wn = w & 1;
    const int g  = lane >> 4, r = lane & 15;

    __shared__ f16 Al[128 * 32];
    __shared__ f16 Bl[128 * 32];

    floatx4 acc[4][4];
    #pragma unroll
    for (int i = 0; i < 4; i++)
        #pragma unroll
        for (int j = 0; j < 4; j++)
            acc[i][j] = (floatx4){0.f, 0.f, 0.f, 0.f};

    for (int k0 = 0; k0 < E_DIM; k0 += 32) {
        #pragma unroll
        for (int it = 0; it < 2; it++) {
            int idx = tid + it * 256;
            int mm = idx >> 2, kc = (idx & 3) * 8;
            const float* s = &x[(size_t)(m0 + mm) * E_DIM + k0 + kc];
            float4 u = *(const float4*)s;
            float4 v = *(const float4*)(s + 4);
            half8 hv = {(f16)u.x,(f16)u.y,(f16)u.z,(f16)u.w,
                        (f16)v.x,(f16)v.y,(f16)v.z,(f16)v.w};
            *(half8*)&Al[mm * 32 + (kc ^ (((mm >> 2) & 3) << 3))] = hv;
        }
        #pragma unroll
        for (int it = 0; it < 2; it++) {
            int idx = tid + it * 256;
            int nn = idx >> 2, kc = (idx & 3) * 8;
            half8 hv = *(const half8*)&WT[(size_t)(n0 + nn) * E_DIM + k0 + kc];
            *(half8*)&Bl[nn * 32 + (kc ^ (((nn >> 2) & 3) << 3))] = hv;
        }
        __syncthreads();

        half8 af[4], bf[4];
        #pragma unroll
        for (int i = 0; i < 4; i++) {
            int row = wm * 64 + i * 16 + r;
            af[i] = *(const half8*)&Al[row * 32 + ((g * 8) ^ (((row >> 2) & 3) << 3))];
        }
        #pragma unroll
        for (int j = 0; j < 4; j++) {
            int row = wn * 64 + j * 16 + r;
            bf[j] = *(const half8*)&Bl[row * 32 + ((g * 8) ^ (((row >> 2) & 3) << 3))];
        }
        #pragma unroll
        for (int i = 0; i < 4; i++)
            #pragma unroll
            for (int j = 0; j < 4; j++)
                acc[i][j] = MFMA16x32(af[i], bf[j], acc[i][j]);
        __syncthreads();
    }

    #pragma unroll
    for (int j = 0; j < 4; j++) {
        int col = n0 + wn * 64 + j * 16 + r;
        float bb = bias[col];
        #pragma unroll
        for (int i = 0; i < 4; i++)
            #pragma unroll
            for (int rr = 0; rr < 4; rr++) {
                int row = m0 + wm * 64 + i * 16 + g * 4 + rr;
                out[(size_t)row * E_DIM + col] = (f16)(acc[i][j][rr] + bb);
            }
    }
}

// ---------------------------------------------------------------------------
// Kernel 2: flash attention. Swapped QK^T + transposed PV, log2-domain
// softmax (Q pre-scaled by log2e), l-sum via ones-MFMA, pkrtz P-pack,
// defer-max (THR = 8 nats = 11.544 in log2), double-buffered K/V.
// QBLK=128, 8 waves x 16 q-rows, grid 512, KVBLK=64.
// ---------------------------------------------------------------------------
__global__ __launch_bounds__(512, 4) void attn(
    const f16* __restrict__ qh, const f16* __restrict__ kh,
    const f16* __restrict__ vh, float* __restrict__ out)
{
    const int flat = blockIdx.x;                 // 512 blocks = 8*64
    const int rb = (flat & 7) * 64 + (flat >> 3);
    const int qt = rb & 15;
    const int hh = (rb >> 4) & 15;
    const int b  = rb >> 8;
    const int q0 = qt * 128;

    const int tid = threadIdx.x;
    const int lane = tid & 63;
    const int w = tid >> 6;                      // 0..7
    const int g = lane >> 4, r = lane & 15;

    __shared__ f16 K_s[2][64 * 64];              // [kv][d], key (kv&7)<<3
    __shared__ f16 V_s[2][64 * 64];              // [d][kv_perm], key ((d^(d>>3))&7)<<3

    const size_t base = ((size_t)b * SEQ) * E_DIM + (size_t)hh * HDIM;

    // Q fragment: row q0 + w*16 + r, pre-scaled by log2e (softmax in log2 domain)
    half8 aq[2];
    {
        const f16* qp = &qh[base + (size_t)(q0 + w * 16 + r) * E_DIM];
        aq[0] = *(const half8*)&qp[g * 8] * (f16)1.44269504f;
        aq[1] = *(const half8*)&qp[32 + g * 8] * (f16)1.44269504f;
    }

    // K staging: wave w stages rows w*8..w*8+8, pre-swizzled source col
    const int klrow = lane >> 3;
    const int kcol = ((lane & 7) ^ klrow) * 8;
    const f16* kg0 = kh + base + (size_t)(w * 8 + klrow) * E_DIM + kcol;

    // V staging: thread handles kv pair {2p,2p+1} x 4 d
    const int vp = tid >> 4, vdc = (tid & 15) * 4;
    const int kv0 = vp * 2;
    const int kvp0 = (kv0 & 3) | (((kv0 >> 4) & 1) << 2) |
                     (((kv0 >> 2) & 3) << 3) | ((kv0 >> 5) << 5);
    const f16* vg0 = vh + base + (size_t)kv0 * E_DIM + vdc;
    // hoisted V LDS offsets (t-invariant)
    int voff[4];
    #pragma unroll
    for (int e = 0; e < 4; e++) {
        int d = vdc + e;
        voff[e] = d * 64 + (kvp0 ^ (((d ^ (d >> 3)) & 7) << 3));
    }

    const half8 ones = {(f16)1.f,(f16)1.f,(f16)1.f,(f16)1.f,
                        (f16)1.f,(f16)1.f,(f16)1.f,(f16)1.f};

    float m_run = -1e30f;
    floatx4 acco[4];
    floatx4 acc5 = (floatx4){0.f, 0.f, 0.f, 0.f};   // l-sum rows (ones-MFMA)
    #pragma unroll
    for (int dj = 0; dj < 4; dj++) acco[dj] = (floatx4){0.f, 0.f, 0.f, 0.f};

    const int NT = SEQ / 64;

    // --- prologue: stage tile 0 into buffer 0 ---
    gll16(kg0, &K_s[0][w * 512]);
    {
        half4 v0 = *(const half4*)vg0;
        half4 v1 = *(const half4*)(vg0 + E_DIM);
        #pragma unroll
        for (int e = 0; e < 4; e++) {
            half2v pr = {v0[e], v1[e]};
            *(half2v*)&V_s[0][voff[e]] = pr;
        }
    }
    __syncthreads();

    for (int t = 0; t < NT; t++) {
        const int cur = t & 1;
        const bool pf = (t + 1 < NT);
        half4 v0n, v1n;
        if (pf) {
            gll16(kg0 + (size_t)(t + 1) * 64 * E_DIM, &K_s[cur ^ 1][w * 512]);
            const f16* vsrc = vg0 + (size_t)(t + 1) * 64 * E_DIM;
            v0n = *(const half4*)vsrc;
            v1n = *(const half4*)(vsrc + E_DIM);
        }

        // --- S^T = K Q^T (log2 domain) : sct[kb][rr] = S[q=r][kv=kb*16+g*4+rr]
        floatx4 sct[4];
        __builtin_amdgcn_s_setprio(1);
        #pragma unroll
        for (int kb = 0; kb < 4; kb++) {
            int kr2 = kb * 16 + r;
            int swk = (kr2 & 7) << 3;
            const f16* kb_ = &K_s[cur][kr2 * 64];
            half8 kf0 = *(const half8*)&kb_[(g * 8) ^ swk];
            half8 kf1 = *(const half8*)&kb_[(32 + g * 8) ^ swk];
            floatx4 c = (floatx4){0.f, 0.f, 0.f, 0.f};
            c = MFMA16x32(kf0, aq[0], c);
            c = MFMA16x32(kf1, aq[1], c);
            sct[kb] = c;
        }
        __builtin_amdgcn_s_setprio(0);

        // --- max reduce (max3-shaped), defer-max THR = 8 nats = 11.544 log2 ---
        float t0 = FMAX3(sct[0][0], sct[0][1], sct[0][2]);
        float t1 = FMAX3(sct[0][3], sct[1][0], sct[1][1]);
        float t2 = FMAX3(sct[1][2], sct[1][3], sct[2][0]);
        float t3 = FMAX3(sct[2][1], sct[2][2], sct[2][3]);
        float t4 = FMAX3(sct[3][0], sct[3][1], sct[3][2]);
        float pm = fmaxf(FMAX3(t0, t1, t2), FMAX3(t3, t4, sct[3][3]));
        pm = fmaxf(pm, __shfl_xor(pm, 16, 64));
        pm = fmaxf(pm, __shfl_xor(pm, 32, 64));
        if (!__all(pm - m_run <= 11.544f)) {
            float mn = fmaxf(m_run, pm);
            float alpha = EXP2F(m_run - mn);
            m_run = mn;
            acc5 *= alpha;
            #pragma unroll
            for (int dj = 0; dj < 4; dj++)
                #pragma unroll
                for (int rr = 0; rr < 4; rr++)
                    acco[dj][rr] *= alpha;
        }

        // --- P = exp2(S - m), packed straight to f16 via pkrtz ---
        union H8 { half8 v; half2v h2[4]; };
        half8 pa[2];
        #pragma unroll
        for (int h = 0; h < 2; h++) {
            H8 u;
            #pragma unroll
            for (int q = 0; q < 2; q++) {   // q=0 -> kb=h*2, q=1 -> kb=h*2+1
                int kb = h * 2 + q;
                u.h2[q * 2 + 0] = pkrtz(
                    EXP2F(sct[kb][0] - m_run), EXP2F(sct[kb][1] - m_run));
                u.h2[q * 2 + 1] = pkrtz(
                    EXP2F(sct[kb][2] - m_run), EXP2F(sct[kb][3] - m_run));
            }
            pa[h] = u.v;
        }

        // --- write prefetched V into next buffer ---
        if (pf) {
            #pragma unroll
            for (int e = 0; e < 4; e++) {
                half2v pr = {v0n[e], v1n[e]};
                *(half2v*)&V_s[cur ^ 1][voff[e]] = pr;
            }
        }

        // --- O^T += V^T P^T ; l-rows += 1^T P^T ---
        __builtin_amdgcn_s_setprio(1);
        #pragma unroll
        for (int dj = 0; dj < 4; dj++) {
            int d = dj * 16 + r;
            int swv = ((d ^ (d >> 3)) & 7) << 3;
            const f16* vb_ = &V_s[cur][d * 64];
            half8 vf0 = *(const half8*)&vb_[(g * 8) ^ swv];
            half8 vf1 = *(const half8*)&vb_[(32 + g * 8) ^ swv];
            acco[dj] = MFMA16x32(vf0, pa[0], acco[dj]);
            acco[dj] = MFMA16x32(vf1, pa[1], acco[dj]);
        }
        acc5 = MFMA16x32(ones, pa[0], acc5);
        acc5 = MFMA16x32(ones, pa[1], acc5);
        __builtin_amdgcn_s_setprio(0);

        __syncthreads();   // next tile's buffers ready; this tile's reads done
    }

    // --- epilogue: acco[dj][rr] = O[q=r][d=dj*16+g*4+rr]; l = acc5[0] ---
    {
        float inv = 1.f / acc5[0];
        int row = q0 + w * 16 + r;
        float* orow = out + (size_t)(b * SEQ + row) * E_DIM + hh * HDIM;
        #pragma unroll
        for (int dj = 0; dj < 4; dj++) {
            float4 st = {acco[dj][0] * inv, acco[dj][1] * inv,
                         acco[dj][2] * inv, acco[dj][3] * inv};
            *(float4*)&orow[dj * 16 + g * 4] = st;
        }
    }
}

extern "C" void kernel_launch(void* const* d_in, const int* in_sizes, int n_in,
                              void* d_out, int out_size, void* d_ws, size_t ws_size,
                              hipStream_t stream) {
    const float* x  = (const float*)d_in[0];
    const float* Wq = (const float*)d_in[1];
    const float* bq = (const float*)d_in[2];
    const float* Wk = (const float*)d_in[3];
    const float* bk = (const float*)d_in[4];
    const float* Wv = (const float*)d_in[5];
    const float* bv = (const float*)d_in[6];
    float* out = (float*)d_out;

    const size_t qkv_elems = (size_t)M_TOT * E_DIM;          // 4M f16 each
    const size_t w_elems   = (size_t)E_DIM * E_DIM;          // 1M f16 each
    f16* qh  = (f16*)d_ws;
    f16* kh  = qh + qkv_elems;
    f16* vh  = kh + qkv_elems;
    f16* WTq = vh + qkv_elems;        // WTq/WTk/WTv contiguous = WTall
    f16* WTk = WTq + w_elems;
    f16* WTv = WTk + w_elems;
    f16* xh  = WTv + w_elems;
    const size_t need_v3  = (3 * qkv_elems + 3 * w_elems + qkv_elems) * sizeof(f16); // 38 MB
    const size_t need_v2  = (3 * qkv_elems + 3 * w_elems) * sizeof(f16);             // 30 MB
    if (ws_size < need_v2) return;

    if (ws_size >= need_v3) {
        cvt_x<<<dim3(M_TOT * E_DIM / (256 * 8)), 256, 0, stream>>>(x, xh);
        transpose_w<<<dim3(16, 16, 3), 256, 0, stream>>>(Wq, Wk, Wv, WTq, WTk, WTv);
        qkv_gemm<<<dim3((E_DIM / 128) * (M_TOT / 128) * 3), 256, 0, stream>>>(
            xh, WTq, bq, bk, bv, qh, kh, vh);
    } else {
        transpose_w<<<dim3(16, 16, 3), 256, 0, stream>>>(Wq, Wk, Wv, WTq, WTk, WTv);
        qkv_proj_v2<<<dim3((E_DIM / 128) * (M_TOT / 128) * 3), 256, 0, stream>>>(
            x, WTq, WTk, WTv, bq, bk, bv, qh, kh, vh);
    }
    attn<<<dim3((SEQ / 128) * NHEADS * BATCH), 512, 0, stream>>>(qh, kh, vh, out);
}

// Round 9
// 162.998 us; speedup vs baseline: 2.4758x; 1.0376x over previous
//
#include <hip/hip_runtime.h>

#define E_DIM 1024
#define NHEADS 16
#define HDIM 64
#define BATCH 2
#define SEQ 2048
#define M_TOT (BATCH*SEQ)   // 4096

typedef _Float16 f16;
typedef _Float16 half4 __attribute__((ext_vector_type(4)));
typedef _Float16 half8 __attribute__((ext_vector_type(8)));
typedef _Float16 half2v __attribute__((ext_vector_type(2)));
typedef float floatx4 __attribute__((ext_vector_type(4)));

#define MFMA16x32(a,b,c) __builtin_amdgcn_mfma_f32_16x16x32_f16((a),(b),(c),0,0,0)
#define EXP2F(x) __builtin_amdgcn_exp2f(x)
#define FMAX3(a,b,c) fmaxf(fmaxf((a),(b)),(c))

// cvt_pkrtz returns __fp16x2; bit-cast to our _Float16x2
__device__ __forceinline__ half2v pkrtz(float a, float b) {
    return __builtin_bit_cast(half2v, __builtin_amdgcn_cvt_pkrtz(a, b));
}

// async global->LDS, 16B per lane, LDS dest = wave-uniform base + lane*16
__device__ __forceinline__ void gll16(const f16* gsrc, f16* ldst) {
    __builtin_amdgcn_global_load_lds(
        (const __attribute__((address_space(1))) void*)gsrc,
        (__attribute__((address_space(3))) void*)ldst, 16, 0, 0);
}

// ---------------------------------------------------------------------------
// Prep (merged): blocks [0,2048): x f32->f16 ; blocks [2048,2816): W->WT f16
// ---------------------------------------------------------------------------
__global__ __launch_bounds__(256) void prep(
    const float* __restrict__ x, f16* __restrict__ xh,
    const float* __restrict__ Wq, const float* __restrict__ Wk,
    const float* __restrict__ Wv,
    f16* __restrict__ WTq, f16* __restrict__ WTk, f16* __restrict__ WTv)
{
    const int tid = threadIdx.x;
    if (blockIdx.x < 2048) {
        size_t i = ((size_t)blockIdx.x * 256 + tid) * 8;
        float4 a = *(const float4*)&x[i];
        float4 b = *(const float4*)&x[i + 4];
        half8 h = {(f16)a.x,(f16)a.y,(f16)a.z,(f16)a.w,
                   (f16)b.x,(f16)b.y,(f16)b.z,(f16)b.w};
        *(half8*)&xh[i] = h;
        return;
    }
    const int f = blockIdx.x - 2048;           // 768 = 3 * 256
    const int z = f >> 8;
    const int k0 = (f & 15) * 64, n0 = ((f >> 4) & 15) * 64;
    const float* W = (z == 0) ? Wq : (z == 1) ? Wk : Wv;
    f16* WT        = (z == 0) ? WTq : (z == 1) ? WTk : WTv;

    __shared__ f16 T[64][68];
    {
        const int tr = tid >> 4, tc = tid & 15;
        float4 f4[4];
        #pragma unroll
        for (int i = 0; i < 4; i++)
            f4[i] = *(const float4*)&W[(size_t)(k0 + tr * 4 + i) * E_DIM + n0 + tc * 4];
        #pragma unroll
        for (int j = 0; j < 4; j++) {
            float e0 = (j==0)?f4[0].x:(j==1)?f4[0].y:(j==2)?f4[0].z:f4[0].w;
            float e1 = (j==0)?f4[1].x:(j==1)?f4[1].y:(j==2)?f4[1].z:f4[1].w;
            float e2 = (j==0)?f4[2].x:(j==1)?f4[2].y:(j==2)?f4[2].z:f4[2].w;
            float e3 = (j==0)?f4[3].x:(j==1)?f4[3].y:(j==2)?f4[3].z:f4[3].w;
            half4 h = {(f16)e0, (f16)e1, (f16)e2, (f16)e3};
            *(half4*)&T[tc * 4 + j][tr * 4] = h;
        }
    }
    __syncthreads();
    {
        const int nn = tid >> 2, kk = (tid & 3) * 16;
        half8 a = *(const half8*)&T[nn][kk];
        half8 b = *(const half8*)&T[nn][kk + 8];
        f16* dst = &WT[(size_t)(n0 + nn) * E_DIM + k0 + kk];
        *(half8*)dst = a;
        *(half8*)(dst + 8) = b;
    }
}

// ---------------------------------------------------------------------------
// Kernel 1: pure-f16 GEMM, m97 structure (unchanged).
// ---------------------------------------------------------------------------
__global__ __launch_bounds__(256) void qkv_gemm(
    const f16* __restrict__ xh, const f16* __restrict__ WTall,
    const float* __restrict__ bq, const float* __restrict__ bk,
    const float* __restrict__ bv,
    f16* __restrict__ qh, f16* __restrict__ kh, f16* __restrict__ vh)
{
    const int flat = blockIdx.x;                  // 768 = 8*96
    const int rb = (flat & 7) * 96 + (flat >> 3);
    const int z   = rb >> 8;
    const int ntl = rb & 7;
    const int mt  = (rb >> 3) & 31;

    const float* bias = (z == 0) ? bq : (z == 1) ? bk : bv;
    f16* out          = (z == 0) ? qh : (z == 1) ? kh : vh;

    const int m0 = mt * 128;
    const int n0g = z * 1024 + ntl * 128;
    const int tid = threadIdx.x;
    const int lane = tid & 63;
    const int w  = tid >> 6;
    const int wm = w >> 1, wn = w & 1;
    const int g  = lane >> 4, r = lane & 15;

    __shared__ f16 Al[128 * 64];
    __shared__ f16 Bl[128 * 64];

    const int lrow = lane >> 3;
    const int lcol = ((lane & 7) ^ lrow) * 8;
    const f16* asrc = xh    + (size_t)(m0  + lrow) * E_DIM + lcol;
    const f16* bsrc = WTall + (size_t)(n0g + lrow) * E_DIM + lcol;

    floatx4 acc[4][4];
    #pragma unroll
    for (int i = 0; i < 4; i++)
        #pragma unroll
        for (int j = 0; j < 4; j++)
            acc[i][j] = (floatx4){0.f, 0.f, 0.f, 0.f};

    for (int k0 = 0; k0 < E_DIM; k0 += 64) {
        if (k0) __syncthreads();
        #pragma unroll
        for (int t = 0; t < 4; t++) {
            int c = w * 4 + t;
            gll16(asrc + (size_t)c * 8 * E_DIM + k0, Al + c * 512);
            gll16(bsrc + (size_t)c * 8 * E_DIM + k0, Bl + c * 512);
        }
        __syncthreads();

        #pragma unroll
        for (int ks = 0; ks < 64; ks += 32) {
            half8 af[4], bf[4];
            #pragma unroll
            for (int i = 0; i < 4; i++) {
                int row = wm * 64 + i * 16 + r;
                af[i] = *(const half8*)&Al[row * 64 + ((ks + g * 8) ^ ((row & 7) << 3))];
            }
            #pragma unroll
            for (int j = 0; j < 4; j++) {
                int row = wn * 64 + j * 16 + r;
                bf[j] = *(const half8*)&Bl[row * 64 + ((ks + g * 8) ^ ((row & 7) << 3))];
            }
            #pragma unroll
            for (int i = 0; i < 4; i++)
                #pragma unroll
                for (int j = 0; j < 4; j++)
                    acc[i][j] = MFMA16x32(af[i], bf[j], acc[i][j]);
        }
    }

    #pragma unroll
    for (int j = 0; j < 4; j++) {
        int col = ntl * 128 + wn * 64 + j * 16 + r;
        float bb = bias[col];
        #pragma unroll
        for (int i = 0; i < 4; i++)
            #pragma unroll
            for (int rr = 0; rr < 4; rr++) {
                int row = m0 + wm * 64 + i * 16 + g * 4 + rr;
                out[(size_t)row * E_DIM + col] = (f16)(acc[i][j][rr] + bb);
            }
    }
}

// ---------------------------------------------------------------------------
// Kernel 2: flash attention, one-tile-ahead QK^T pipeline (T15 analog).
// Iteration t: QK^T(t+1)[MFMA] -> gll16 K(t+2) -> softmax(t)[VALU, overlaps
// MFMA latency] -> V(t+1) LDS-write + V(t+2) reg-load -> PV(t) -> barrier.
// Buffers: K_s[(t+1)&1] read by QK^T(t+1); K(t+2) staged into K_s[t&1]
// (last read by QK^T(t) one barrier ago). V analogous. Manual x2 unroll with
// named state (sA/sB, vrP/vrQ) to keep everything in registers.
// ---------------------------------------------------------------------------
__global__ __launch_bounds__(512, 4) void attn(
    const f16* __restrict__ qh, const f16* __restrict__ kh,
    const f16* __restrict__ vh, float* __restrict__ out)
{
    const int flat = blockIdx.x;                 // 512 blocks = 8*64
    const int rb = (flat & 7) * 64 + (flat >> 3);
    const int qt = rb & 15;
    const int hh = (rb >> 4) & 15;
    const int b  = rb >> 8;
    const int q0 = qt * 128;

    const int tid = threadIdx.x;
    const int lane = tid & 63;
    const int w = tid >> 6;                      // 0..7
    const int g = lane >> 4, r = lane & 15;

    __shared__ f16 K_s[2][64 * 64];              // [kv][d], key (kv&7)<<3
    __shared__ f16 V_s[2][64 * 64];              // [d][kv_perm], key ((d^(d>>3))&7)<<3

    const size_t base = ((size_t)b * SEQ) * E_DIM + (size_t)hh * HDIM;

    // Q fragment: row q0 + w*16 + r, pre-scaled by log2e
    half8 aq[2];
    {
        const f16* qp = &qh[base + (size_t)(q0 + w * 16 + r) * E_DIM];
        aq[0] = *(const half8*)&qp[g * 8] * (f16)1.44269504f;
        aq[1] = *(const half8*)&qp[32 + g * 8] * (f16)1.44269504f;
    }

    // K staging: wave w stages rows w*8..w*8+8, pre-swizzled source col
    const int klrow = lane >> 3;
    const int kcol = ((lane & 7) ^ klrow) * 8;
    const f16* kg0 = kh + base + (size_t)(w * 8 + klrow) * E_DIM + kcol;

    // V staging: thread handles kv pair {2p,2p+1} x 4 d
    const int vp = tid >> 4, vdc = (tid & 15) * 4;
    const int kv0 = vp * 2;
    const int kvp0 = (kv0 & 3) | (((kv0 >> 4) & 1) << 2) |
                     (((kv0 >> 2) & 3) << 3) | ((kv0 >> 5) << 5);
    const f16* vg0 = vh + base + (size_t)kv0 * E_DIM + vdc;
    int voff[4];
    #pragma unroll
    for (int e = 0; e < 4; e++) {
        int d = vdc + e;
        voff[e] = d * 64 + (kvp0 ^ (((d ^ (d >> 3)) & 7) << 3));
    }

    const half8 ones = {(f16)1.f,(f16)1.f,(f16)1.f,(f16)1.f,
                        (f16)1.f,(f16)1.f,(f16)1.f,(f16)1.f};

    float m_run = -1e30f;
    floatx4 acco[4];
    floatx4 acc5 = (floatx4){0.f, 0.f, 0.f, 0.f};
    #pragma unroll
    for (int dj = 0; dj < 4; dj++) acco[dj] = (floatx4){0.f, 0.f, 0.f, 0.f};

    const int NT = SEQ / 64;

    floatx4 sA[4], sB[4];
    half4 vP0, vP1, vQ0, vQ1;

    // --- prologue ---
    gll16(kg0, &K_s[0][w * 512]);
    {   // V(0) direct to LDS
        half4 v0 = *(const half4*)vg0;
        half4 v1 = *(const half4*)(vg0 + E_DIM);
        #pragma unroll
        for (int e = 0; e < 4; e++) {
            half2v pr = {v0[e], v1[e]};
            *(half2v*)&V_s[0][voff[e]] = pr;
        }
    }
    __syncthreads();
    // QK^T(0) -> sA
    #pragma unroll
    for (int kb = 0; kb < 4; kb++) {
        int kr2 = kb * 16 + r;
        int swk = (kr2 & 7) << 3;
        const f16* kb_ = &K_s[0][kr2 * 64];
        half8 kf0 = *(const half8*)&kb_[(g * 8) ^ swk];
        half8 kf1 = *(const half8*)&kb_[(32 + g * 8) ^ swk];
        floatx4 c = (floatx4){0.f, 0.f, 0.f, 0.f};
        c = MFMA16x32(kf0, aq[0], c);
        c = MFMA16x32(kf1, aq[1], c);
        sA[kb] = c;
    }
    gll16(kg0 + (size_t)64 * E_DIM, &K_s[1][w * 512]);   // K(1)
    {   // V(1) -> regs
        const f16* vsrc = vg0 + (size_t)64 * E_DIM;
        vP0 = *(const half4*)vsrc;
        vP1 = *(const half4*)(vsrc + E_DIM);
    }
    __syncthreads();

#define ATTN_ITER(T, SC, SN, VW0, VW1, VL0, VL1, CUR)                          \
    do {                                                                       \
        /* A: QK^T(T+1) from K_s[CUR^1] */                                     \
        if ((T) + 1 < NT) {                                                    \
            _Pragma("unroll")                                                  \
            for (int kb = 0; kb < 4; kb++) {                                   \
                int kr2 = kb * 16 + r;                                         \
                int swk = (kr2 & 7) << 3;                                      \
                const f16* kb_ = &K_s[(CUR) ^ 1][kr2 * 64];                    \
                half8 kf0 = *(const half8*)&kb_[(g * 8) ^ swk];                \
                half8 kf1 = *(const half8*)&kb_[(32 + g * 8) ^ swk];           \
                floatx4 c = (floatx4){0.f, 0.f, 0.f, 0.f};                     \
                c = MFMA16x32(kf0, aq[0], c);                                  \
                c = MFMA16x32(kf1, aq[1], c);                                  \
                SN[kb] = c;                                                    \
            }                                                                  \
        }                                                                      \
        /* B: stage K(T+2) into K_s[CUR] */                                    \
        if ((T) + 2 < NT)                                                      \
            gll16(kg0 + (size_t)((T) + 2) * 64 * E_DIM, &K_s[CUR][w * 512]);   \
        /* C: softmax(T) on SC (overlaps A's MFMA latency) */                  \
        {                                                                      \
            float t0 = FMAX3(SC[0][0], SC[0][1], SC[0][2]);                    \
            float t1 = FMAX3(SC[0][3], SC[1][0], SC[1][1]);                    \
            float t2 = FMAX3(SC[1][2], SC[1][3], SC[2][0]);                    \
            float t3 = FMAX3(SC[2][1], SC[2][2], SC[2][3]);                    \
            float t4 = FMAX3(SC[3][0], SC[3][1], SC[3][2]);                    \
            float pm = fmaxf(FMAX3(t0, t1, t2), FMAX3(t3, t4, SC[3][3]));      \
            pm = fmaxf(pm, __shfl_xor(pm, 16, 64));                            \
            pm = fmaxf(pm, __shfl_xor(pm, 32, 64));                            \
            if (!__all(pm - m_run <= 11.544f)) {                               \
                float mn = fmaxf(m_run, pm);                                   \
                float alpha = EXP2F(m_run - mn);                               \
                m_run = mn;                                                    \
                acc5 *= alpha;                                                 \
                _Pragma("unroll")                                              \
                for (int dj = 0; dj < 4; dj++)                                 \
                    _Pragma("unroll")                                          \
                    for (int rr = 0; rr < 4; rr++)                             \
                        acco[dj][rr] *= alpha;                                 \
            }                                                                  \
        }                                                                      \
        {                                                                      \
            union H8 { half8 v; half2v h2[4]; };                               \
            _Pragma("unroll")                                                  \
            for (int h = 0; h < 2; h++) {                                      \
                H8 u;                                                          \
                _Pragma("unroll")                                              \
                for (int q = 0; q < 2; q++) {                                  \
                    int kb = h * 2 + q;                                        \
                    u.h2[q * 2 + 0] = pkrtz(EXP2F(SC[kb][0] - m_run),          \
                                            EXP2F(SC[kb][1] - m_run));         \
                    u.h2[q * 2 + 1] = pkrtz(EXP2F(SC[kb][2] - m_run),          \
                                            EXP2F(SC[kb][3] - m_run));         \
                }                                                              \
                pa[h] = u.v;                                                   \
            }                                                                  \
        }                                                                      \
        /* D: V(T+1) regs -> V_s[CUR^1]; V(T+2) -> regs */                     \
        if ((T) + 1 < NT) {                                                    \
            _Pragma("unroll")                                                  \
            for (int e = 0; e < 4; e++) {                                      \
                half2v pr = {VW0[e], VW1[e]};                                  \
                *(half2v*)&V_s[(CUR) ^ 1][voff[e]] = pr;                       \
            }                                                                  \
        }                                                                      \
        if ((T) + 2 < NT) {                                                    \
            const f16* vsrc = vg0 + (size_t)((T) + 2) * 64 * E_DIM;            \
            VL0 = *(const half4*)vsrc;                                         \
            VL1 = *(const half4*)(vsrc + E_DIM);                               \
        }                                                                      \
        /* E: PV(T) from V_s[CUR]; l-sum */                                    \
        __builtin_amdgcn_s_setprio(1);                                         \
        _Pragma("unroll")                                                      \
        for (int dj = 0; dj < 4; dj++) {                                       \
            int d = dj * 16 + r;                                               \
            int swv = ((d ^ (d >> 3)) & 7) << 3;                               \
            const f16* vb_ = &V_s[CUR][d * 64];                                \
            half8 vf0 = *(const half8*)&vb_[(g * 8) ^ swv];                    \
            half8 vf1 = *(const half8*)&vb_[(32 + g * 8) ^ swv];               \
            acco[dj] = MFMA16x32(vf0, pa[0], acco[dj]);                        \
            acco[dj] = MFMA16x32(vf1, pa[1], acco[dj]);                        \
        }                                                                      \
        acc5 = MFMA16x32(ones, pa[0], acc5);                                   \
        acc5 = MFMA16x32(ones, pa[1], acc5);                                   \
        __builtin_amdgcn_s_setprio(0);                                         \
        __syncthreads();                                                       \
    } while (0)

    for (int t = 0; t < NT; t += 2) {
        half8 pa[2];
        ATTN_ITER(t,     sA, sB, vP0, vP1, vQ0, vQ1, 0);
        ATTN_ITER(t + 1, sB, sA, vQ0, vQ1, vP0, vP1, 1);
    }
#undef ATTN_ITER

    // --- epilogue ---
    {
        float inv = 1.f / acc5[0];
        int row = q0 + w * 16 + r;
        float* orow = out + (size_t)(b * SEQ + row) * E_DIM + hh * HDIM;
        #pragma unroll
        for (int dj = 0; dj < 4; dj++) {
            float4 st = {acco[dj][0] * inv, acco[dj][1] * inv,
                         acco[dj][2] * inv, acco[dj][3] * inv};
            *(float4*)&orow[dj * 16 + g * 4] = st;
        }
    }
}

extern "C" void kernel_launch(void* const* d_in, const int* in_sizes, int n_in,
                              void* d_out, int out_size, void* d_ws, size_t ws_size,
                              hipStream_t stream) {
    const float* x  = (const float*)d_in[0];
    const float* Wq = (const float*)d_in[1];
    const float* bq = (const float*)d_in[2];
    const float* Wk = (const float*)d_in[3];
    const float* bk = (const float*)d_in[4];
    const float* Wv = (const float*)d_in[5];
    const float* bv = (const float*)d_in[6];
    float* out = (float*)d_out;

    const size_t qkv_elems = (size_t)M_TOT * E_DIM;          // 4M f16 each
    const size_t w_elems   = (size_t)E_DIM * E_DIM;          // 1M f16 each
    f16* qh  = (f16*)d_ws;
    f16* kh  = qh + qkv_elems;
    f16* vh  = kh + qkv_elems;
    f16* WTq = vh + qkv_elems;        // WTq/WTk/WTv contiguous = WTall
    f16* WTk = WTq + w_elems;
    f16* WTv = WTk + w_elems;
    f16* xh  = WTv + w_elems;
    const size_t need = (4 * qkv_elems + 3 * w_elems) * sizeof(f16); // 38 MB
    if (ws_size < need) return;

    prep<<<dim3(2048 + 768), 256, 0, stream>>>(x, xh, Wq, Wk, Wv, WTq, WTk, WTv);
    qkv_gemm<<<dim3((E_DIM / 128) * (M_TOT / 128) * 3), 256, 0, stream>>>(
        xh, WTq, bq, bk, bv, qh, kh, vh);
    attn<<<dim3((SEQ / 128) * NHEADS * BATCH), 512, 0, stream>>>(qh, kh, vh, out);
}